// Round 13
// baseline (201.735 us; speedup 1.0000x reference)
//
#include <hip/hip_runtime.h>
#include <hip/hip_fp16.h>

typedef _Float16 f16;
using frag16 = __attribute__((ext_vector_type(8))) _Float16;  // 8 f16 (4 VGPRs)
using f32x4  = __attribute__((ext_vector_type(4))) float;     // MFMA accumulator

// async global->LDS, 16B per lane.
__device__ __forceinline__ void gload_lds16(const void* g, void* l) {
    __builtin_amdgcn_global_load_lds(
        (const __attribute__((address_space(1))) void*)g,
        (__attribute__((address_space(3))) void*)l, 16, 0, 0);
}

// ---------------------------------------------------------------------------
// fp32 -> f16 convert for all three weight matrices in one launch.
__global__ __launch_bounds__(256) void cvt3_f16(const float* __restrict__ Wq,
                                                const float* __restrict__ Wk,
                                                const float* __restrict__ Wv,
                                                f16* __restrict__ out) {
    int i = blockIdx.x * 256 + threadIdx.x;     // 0..786431
    const float* src = (i < 262144) ? Wq : (i < 524288) ? Wk : Wv;
    out[i] = (f16)src[i & 262143];
}

// ---------------------------------------------------------------------------
// x [B][512][4096] fp32 -> xb [B][4096][512] f16  (64x64 LDS tile)
__global__ __launch_bounds__(256) void transpose_f32_f16(const float* __restrict__ in,
                                                         f16* __restrict__ out) {
    __shared__ float t[64][65];
    const int b = blockIdx.z;
    const int d0 = blockIdx.x * 64, l0 = blockIdx.y * 64;
    const float* ip = in + (size_t)b * 512 * 4096;
    f16* op = out + (size_t)b * 4096 * 512;
    const int tx = threadIdx.x & 63, ty = threadIdx.x >> 6;
#pragma unroll
    for (int r = 0; r < 16; ++r) {
        int d = r * 4 + ty;
        t[d][tx] = ip[(size_t)(d0 + d) * 4096 + l0 + tx];
    }
    __syncthreads();
#pragma unroll
    for (int it = 0; it < 4; ++it) {
        int idx = it * 256 + threadIdx.x;
        int l = idx >> 4, dq = (idx & 15) * 4;
        union { f16 h[4]; unsigned long long u; } pk;
        pk.h[0] = (f16)t[dq + 0][l];
        pk.h[1] = (f16)t[dq + 1][l];
        pk.h[2] = (f16)t[dq + 2][l];
        pk.h[3] = (f16)t[dq + 3][l];
        *reinterpret_cast<unsigned long long*>(&op[(size_t)(l0 + l) * 512 + d0 + dq]) = pk.u;
    }
}

// ---------------------------------------------------------------------------
// row softmax, len=4096: fp32 in -> f16 probs. one block (256 thr) per row
__global__ __launch_bounds__(256) void softmax4096(const float* __restrict__ S,
                                                   f16* __restrict__ P) {
    const float* s = S + (size_t)blockIdx.x * 4096;
    f16* p = P + (size_t)blockIdx.x * 4096;
    const int tid = threadIdx.x;
    float v[16];
    float mx = -3.0e38f;
#pragma unroll
    for (int i = 0; i < 16; ++i) { v[i] = s[i * 256 + tid]; mx = fmaxf(mx, v[i]); }
#pragma unroll
    for (int o = 32; o; o >>= 1) mx = fmaxf(mx, __shfl_xor(mx, o));
    __shared__ float redm[4];
    __shared__ float reds[4];
    if ((tid & 63) == 0) redm[tid >> 6] = mx;
    __syncthreads();
    mx = fmaxf(fmaxf(redm[0], redm[1]), fmaxf(redm[2], redm[3]));
    float sum = 0.f;
#pragma unroll
    for (int i = 0; i < 16; ++i) { v[i] = __expf(v[i] - mx); sum += v[i]; }
#pragma unroll
    for (int o = 32; o; o >>= 1) sum += __shfl_xor(sum, o);
    if ((tid & 63) == 0) reds[tid >> 6] = sum;
    __syncthreads();
    sum = reds[0] + reds[1] + reds[2] + reds[3];
    float inv = 1.f / sum;
#pragma unroll
    for (int i = 0; i < 16; ++i) p[i * 256 + tid] = (f16)(v[i] * inv);
}

// ---------------------------------------------------------------------------
// Fused QKV projection — 8-wave / 512-thread variant.
// Tile 128x128, wave grid 2m x 4n, wave tile 64x32, acc[4][2] (32 acc regs).
// Total regs/wave ~100 -> 4 waves/SIMD (vs 2 at the old 188) -> 2x resident
// waves to hide the per-K-step vmcnt(0) barrier drain.
// XCD grouping in grid shape: grid dim3(8, 12, 32); id%8 == blockIdx.x is the
// XCD slot; m_tile = z*8 + x, n_tile = y (A-panel L2-resident per XCD).
// n0b <  1024 : qk [32768][1024] (+bias) + fused AdaptiveAvgPool (q-part)
// n0b >= 1024 : vT[b][d][l] transposed (+bv)
__global__ __launch_bounds__(512) void gemm_qkv(
    const f16* __restrict__ xb, const f16* __restrict__ w,
    const float* __restrict__ bq, const float* __restrict__ bk,
    const float* __restrict__ bv,
    f16* __restrict__ qk, f16* __restrict__ vT, f16* __restrict__ a)
{
    __shared__ __align__(16) char smem[34816];   // 32KB staging / 34KB f16 epilogue tile
    f16* lA = (f16*)smem;                        // [128][64]
    f16* lB = (f16*)(smem + 16384);              // [128][64]

    const int tid = threadIdx.x;                 // 0..511
    const int lane = tid & 63, wave = tid >> 6;  // 8 waves
    const int wm = wave >> 2, wn = wave & 3;     // 2m x 4n

    const int m0b = ((blockIdx.z << 3) + blockIdx.x) << 7;   // m_tile*128
    const int n0b = blockIdx.y << 7;                          // n_tile*128

    const int lrow = lane & 15, kgrp = (lane >> 4) * 8;

    // staging: 512 threads cover 1024 chunks of 16B per matrix (2 each)
    const int tr = tid >> 3, tc = (tid & 7) * 8;  // rows 0-63; +64 for chunk 2
    const f16* gA = xb + (size_t)(m0b + tr) * 512 + tc;
    const f16* gB = w  + (size_t)(n0b + tr) * 512 + tc;
    char* sAp = smem + tid * 16;
    char* sBp = smem + 16384 + tid * 16;

    f32x4 acc[4][2] = {};
#pragma unroll 1
    for (int k0 = 0; k0 < 512; k0 += 64) {
        gload_lds16(gA + k0,                     sAp);
        gload_lds16(gA + (size_t)64 * 512 + k0,  sAp + 8192);
        gload_lds16(gB + k0,                     sBp);
        gload_lds16(gB + (size_t)64 * 512 + k0,  sBp + 8192);
        __syncthreads();
        const f16* la = lA + (wm * 64 + lrow) * 64 + kgrp;
        const f16* lb = lB + (wn * 32 + lrow) * 64 + kgrp;
#pragma unroll
        for (int kk = 0; kk < 2; ++kk) {
            frag16 af[4], bf[2];
#pragma unroll
            for (int i = 0; i < 4; ++i) af[i] = *(const frag16*)(la + i * 16 * 64 + kk * 32);
#pragma unroll
            for (int j = 0; j < 2; ++j) bf[j] = *(const frag16*)(lb + j * 16 * 64 + kk * 32);
#pragma unroll
            for (int i = 0; i < 4; ++i)
#pragma unroll
                for (int j = 0; j < 2; ++j)
                    acc[i][j] = __builtin_amdgcn_mfma_f32_16x16x32_f16(af[i], bf[j], acc[i][j], 0, 0, 0);
        }
        __syncthreads();
    }

    const int rbase = (lane >> 4) * 4;
    if (n0b < 1024) {
        const float* bptr = (n0b < 512) ? bq : bk;

        // fused AdaptiveAvgPool (q-part only): wave rows wm*64..+63 cover
        // pool groups pbase (i=0,1) and pbase+1 (i=2,3)
        if (n0b < 512) {
            const int b = m0b >> 12;
            const int pbase = ((m0b & 4095) >> 5) + wm * 2;
#pragma unroll
            for (int j = 0; j < 2; ++j) {
                int d = n0b + wn * 32 + j * 16 + lrow;
                float badd = bptr[d];
                float s0 = 0.f, s1 = 0.f;
#pragma unroll
                for (int r = 0; r < 4; ++r) {
                    s0 += acc[0][j][r] + acc[1][j][r];
                    s1 += acc[2][j][r] + acc[3][j][r];
                }
                s0 += __shfl_xor(s0, 16); s0 += __shfl_xor(s0, 32);
                s1 += __shfl_xor(s1, 16); s1 += __shfl_xor(s1, 32);
                if (lane < 16) {
                    a[((size_t)(b * 128 + pbase)     * 512) + d] = (f16)(s0 * 0.03125f + badd);
                    a[((size_t)(b * 128 + pbase + 1) * 512) + d] = (f16)(s1 * 0.03125f + badd);
                }
            }
        }

        // coalesced qk store via LDS staging: f16 tile [128][136]
        f16* lt = (f16*)smem;
#pragma unroll
        for (int j = 0; j < 2; ++j) {
            int col = wn * 32 + j * 16 + lrow;
            float badd = bptr[(n0b + col) & 511];
#pragma unroll
            for (int i = 0; i < 4; ++i) {
                int row = wm * 64 + i * 16 + rbase;
#pragma unroll
                for (int r = 0; r < 4; ++r)
                    lt[(row + r) * 136 + col] = (f16)(acc[i][j][r] + badd);
            }
        }
        __syncthreads();
#pragma unroll
        for (int it = 0; it < 4; ++it) {
            int cu = it * 512 + tid;            // 2048 chunks of 8 f16
            int row = cu >> 4, c8 = (cu & 15) * 8;
            *reinterpret_cast<uint4*>(&qk[(size_t)(m0b + row) * 1024 + n0b + c8]) =
                *reinterpret_cast<const uint4*>(&lt[row * 136 + c8]);
        }
    } else {
        const int b = m0b >> 12, l0 = m0b & 4095;
        const int d0 = n0b - 1024;
        f16* vout = vT + (size_t)b * 2097152 + l0;
        float* lt = (float*)smem;   // [64][132] fp32
#pragma unroll
        for (int h = 0; h < 2; ++h) {
            if ((wn >> 1) == h) {
#pragma unroll
                for (int i = 0; i < 4; ++i)
#pragma unroll
                    for (int j = 0; j < 2; ++j)
#pragma unroll
                        for (int r = 0; r < 4; ++r)
                            lt[((wn & 1) * 32 + j * 16 + lrow) * 132 + wm * 64 + i * 16 + rbase + r]
                                = acc[i][j][r];
            }
            __syncthreads();
#pragma unroll
            for (int it = 0; it < 16; ++it) {
                int idx = it * 512 + tid;       // 8192 = 64 x 128
                int nl = idx >> 7, ml = idx & 127;
                int d = d0 + h * 64 + nl;
                float val = lt[nl * 132 + ml] + bv[d];
                vout[(size_t)d * 4096 + ml] = (f16)val;
            }
            __syncthreads();
        }
    }
}

// ---------------------------------------------------------------------------
// Generic NT GEMM (R7 structure): C[m][n] = sum_k A[m][k]*B[n][k].
// Tile 128x128, BK=64, 4 waves (2x2). splitk partials; TRANS_OUT: out[n][m].
template<bool OUT_F16, bool BIAS, bool TRANS_OUT>
__global__ __launch_bounds__(256) void gemm_lds(
    const f16* __restrict__ A, const f16* __restrict__ B,
    const float* __restrict__ bias, void* __restrict__ C,
    int K, int lda, int ldb, int ldc,
    long long sA, long long sB, long long sC, int splitk)
{
    __shared__ __align__(16) char smem[33792];
    f16* lA = (f16*)smem;                        // [128][64]
    f16* lB = (f16*)(smem + 16384);              // [128][64]

    const int z = blockIdx.z;
    const int batch = z / splitk;
    const int ks = z - batch * splitk;
    const int Ksub = K / splitk;
    const int kbeg = ks * Ksub;

    const f16* Ab = A + (size_t)batch * sA;
    const f16* Bb = B + (size_t)batch * sB;

    const int tid = threadIdx.x;
    const int lane = tid & 63, wave = tid >> 6;
    const int wm = wave >> 1, wn = wave & 1;
    const int m0b = blockIdx.x * 128, n0b = blockIdx.y * 128;
    const int lrow = lane & 15, kgrp = (lane >> 4) * 8;

    const int tr = tid >> 3, tc = (tid & 7) * 8;
    const f16* gA = Ab + (size_t)(m0b + tr) * lda + tc + kbeg;
    const f16* gB = Bb + (size_t)(n0b + tr) * ldb + tc + kbeg;
    char* sAp = smem + tid * 16;
    char* sBp = smem + 16384 + tid * 16;

    f32x4 acc[4][4] = {};
    for (int k0 = 0; k0 < Ksub; k0 += 64) {
#pragma unroll
        for (int i = 0; i < 4; ++i) {
            gload_lds16(gA + (size_t)(i * 32) * lda + k0, sAp + i * 4096);
            gload_lds16(gB + (size_t)(i * 32) * ldb + k0, sBp + i * 4096);
        }
        __syncthreads();
        const f16* la = lA + (wm * 64 + lrow) * 64 + kgrp;
        const f16* lb = lB + (wn * 64 + lrow) * 64 + kgrp;
#pragma unroll
        for (int kk = 0; kk < 2; ++kk) {
            frag16 af[4], bf[4];
#pragma unroll
            for (int i = 0; i < 4; ++i) af[i] = *(const frag16*)(la + i * 16 * 64 + kk * 32);
#pragma unroll
            for (int j = 0; j < 4; ++j) bf[j] = *(const frag16*)(lb + j * 16 * 64 + kk * 32);
#pragma unroll
            for (int i = 0; i < 4; ++i)
#pragma unroll
                for (int j = 0; j < 4; ++j)
                    acc[i][j] = __builtin_amdgcn_mfma_f32_16x16x32_f16(af[i], bf[j], acc[i][j], 0, 0, 0);
        }
        __syncthreads();
    }

    const int rbase = (lane >> 4) * 4;
    const size_t cb = (size_t)z * sC;
    if constexpr (TRANS_OUT) {
        float* lt = (float*)smem;   // [64][132]
#pragma unroll
        for (int h = 0; h < 2; ++h) {
            if (wn == h) {
#pragma unroll
                for (int i = 0; i < 4; ++i)
#pragma unroll
                    for (int j = 0; j < 4; ++j)
#pragma unroll
                        for (int r = 0; r < 4; ++r)
                            lt[(j * 16 + lrow) * 132 + wm * 64 + i * 16 + rbase + r] = acc[i][j][r];
            }
            __syncthreads();
#pragma unroll
            for (int it = 0; it < 32; ++it) {
                int idx = it * 256 + tid;
                int nl = idx >> 7, ml = idx & 127;
                int n = n0b + h * 64 + nl;
                float val = lt[nl * 132 + ml] + (BIAS ? bias[n] : 0.f);
                size_t o = cb + (size_t)n * ldc + m0b + ml;
                if constexpr (OUT_F16) ((f16*)C)[o] = (f16)val;
                else                   ((float*)C)[o] = val;
            }
            __syncthreads();
        }
    } else {
#pragma unroll
        for (int j = 0; j < 4; ++j) {
            int col = n0b + wn * 64 + j * 16 + lrow;
            float badd = BIAS ? bias[col] : 0.f;
#pragma unroll
            for (int i = 0; i < 4; ++i) {
                int row = m0b + wm * 64 + i * 16 + rbase;
#pragma unroll
                for (int r = 0; r < 4; ++r) {
                    float val = acc[i][j][r] + badd;
                    size_t o = cb + (size_t)(row + r) * ldc + col;
                    if constexpr (OUT_F16) ((f16*)C)[o] = (f16)val;
                    else                   ((float*)C)[o] = val;
                }
            }
        }
    }
}

// ---------------------------------------------------------------------------
// split-K reduce for PV: cT[b][d][p] = sum_{s<8} Pp[b*8+s][p][d], fp32 -> f16
__global__ __launch_bounds__(256) void reduce_pv(const float* __restrict__ Pp,
                                                 f16* __restrict__ cT) {
    int idx = blockIdx.x * 256 + threadIdx.x;   // 524288 total
    int d = idx & 511, p = (idx >> 9) & 127, b = idx >> 16;
    float s = 0.f;
#pragma unroll
    for (int k = 0; k < 8; ++k)
        s += Pp[(size_t)(b * 8 + k) * 65536 + p * 512 + d];
    cT[(size_t)b * 65536 + d * 128 + p] = (f16)s;
}

// ---------------------------------------------------------------------------
// Fused stage-2: S2 = q.a^T -> in-register softmax -> P2 (f16 LDS) ->
// r = P2.cT^T -> transposed fp32 store to out[b][d][l]. grid dim3(32, 8).
__global__ __launch_bounds__(256) void attn2(
    const f16* __restrict__ qk, const f16* __restrict__ ab,
    const f16* __restrict__ cT, float* __restrict__ out)
{
    __shared__ __align__(16) char smem[69632];
    float* scr = (float*)(smem + 33280);
    f16*   P2  = (f16*)(smem + 34816);

    const int tid = threadIdx.x;
    const int lane = tid & 63, wave = tid >> 6;
    const int wm = wave >> 1, wn = wave & 1;
    const int l0 = blockIdx.x * 128;
    const int b  = blockIdx.y;
    const int lrow = lane & 15, kgrp = (lane >> 4) * 8, rbase = (lane >> 4) * 4;
    const int tr = tid >> 3, tc = (tid & 7) * 8;

    char* sAp = smem + tid * 16;
    char* sBp = smem + 16384 + tid * 16;

    // ---- phase 1: S2 tile = q . a^T ----
    const f16* gA = qk + (size_t)b * 4194304 + (size_t)(l0 + tr) * 1024 + tc;
    const f16* gB = ab + (size_t)b * 65536  + (size_t)tr * 512 + tc;

    f32x4 acc[4][4] = {};
#pragma unroll 1
    for (int k0 = 0; k0 < 512; k0 += 64) {
#pragma unroll
        for (int i = 0; i < 4; ++i) {
            gload_lds16(gA + (size_t)(i * 32) * 1024 + k0, sAp + i * 4096);
            gload_lds16(gB + (size_t)(i * 32) * 512  + k0, sBp + i * 4096);
        }
        __syncthreads();
        const f16* la = (const f16*)smem + (wm * 64 + lrow) * 64 + kgrp;
        const f16* lb = (const f16*)(smem + 16384) + (wn * 64 + lrow) * 64 + kgrp;
#pragma unroll
        for (int kk = 0; kk < 2; ++kk) {
            frag16 af[4], bf[4];
#pragma unroll
            for (int i = 0; i < 4; ++i) af[i] = *(const frag16*)(la + i * 16 * 64 + kk * 32);
#pragma unroll
            for (int j = 0; j < 4; ++j) bf[j] = *(const frag16*)(lb + j * 16 * 64 + kk * 32);
#pragma unroll
            for (int i = 0; i < 4; ++i)
#pragma unroll
                for (int j = 0; j < 4; ++j)
                    acc[i][j] = __builtin_amdgcn_mfma_f32_16x16x32_f16(af[i], bf[j], acc[i][j], 0, 0, 0);
        }
        __syncthreads();
    }

    // ---- phase 2: softmax over N=128 (p), rows are l ----
    float mx[4][4];
#pragma unroll
    for (int i = 0; i < 4; ++i)
#pragma unroll
        for (int r = 0; r < 4; ++r) {
            float m = fmaxf(fmaxf(acc[i][0][r], acc[i][1][r]),
                            fmaxf(acc[i][2][r], acc[i][3][r]));
            m = fmaxf(m, __shfl_xor(m, 1));
            m = fmaxf(m, __shfl_xor(m, 2));
            m = fmaxf(m, __shfl_xor(m, 4));
            m = fmaxf(m, __shfl_xor(m, 8));
            mx[i][r] = m;
        }
    if ((lane & 15) == 0) {
#pragma unroll
        for (int i = 0; i < 4; ++i)
#pragma unroll
            for (int r = 0; r < 4; ++r)
                scr[wn * 128 + wm * 64 + i * 16 + rbase + r] = mx[i][r];
    }
    __syncthreads();
    float rowm[4][4];
#pragma unroll
    for (int i = 0; i < 4; ++i)
#pragma unroll
        for (int r = 0; r < 4; ++r) {
            int row = wm * 64 + i * 16 + rbase + r;
            rowm[i][r] = fmaxf(scr[row], scr[128 + row]);
        }
    __syncthreads();
    float sum[4][4];
#pragma unroll
    for (int i = 0; i < 4; ++i)
#pragma unroll
        for (int r = 0; r < 4; ++r) {
            float s = 0.f;
#pragma unroll
            for (int j = 0; j < 4; ++j) {
                float p = __expf(acc[i][j][r] - rowm[i][r]);
                acc[i][j][r] = p;
                s += p;
            }
            s += __shfl_xor(s, 1);
            s += __shfl_xor(s, 2);
            s += __shfl_xor(s, 4);
            s += __shfl_xor(s, 8);
            sum[i][r] = s;
        }
    if ((lane & 15) == 0) {
#pragma unroll
        for (int i = 0; i < 4; ++i)
#pragma unroll
            for (int r = 0; r < 4; ++r)
                scr[wn * 128 + wm * 64 + i * 16 + rbase + r] = sum[i][r];
    }
    __syncthreads();
#pragma unroll
    for (int i = 0; i < 4; ++i)
#pragma unroll
        for (int r = 0; r < 4; ++r) {
            int row = wm * 64 + i * 16 + rbase + r;
            float inv = 1.f / (scr[row] + scr[128 + row]);
#pragma unroll
            for (int j = 0; j < 4; ++j)
                P2[row * 136 + wn * 64 + j * 16 + lrow] = (f16)(acc[i][j][r] * inv);
        }
    __syncthreads();

    // ---- phase 3: r = P2 . cT^T, 4 chunks of 128 d-cols, K=128 (p) ----
    const f16* gC = cT + (size_t)b * 65536;
    float* outb = out + (size_t)b * 512 * 4096;
#pragma unroll 1
    for (int c = 0; c < 4; ++c) {
        const int d0 = c * 128;
#pragma unroll
        for (int i = 0; i < 4; ++i) {
            gload_lds16(gC + (size_t)(d0 + tr + i * 32) * 128 + tc,      sAp + i * 4096);
            gload_lds16(gC + (size_t)(d0 + tr + i * 32) * 128 + tc + 64, sBp + i * 4096);
        }
        __syncthreads();
        f32x4 a2[4][4] = {};
#pragma unroll
        for (int half = 0; half < 2; ++half) {
            const f16* lb = (const f16*)(smem + half * 16384) + (wn * 64 + lrow) * 64 + kgrp;
            const f16* lpa = P2 + (wm * 64 + lrow) * 136 + half * 64 + kgrp;
#pragma unroll
            for (int kk = 0; kk < 2; ++kk) {
                frag16 af[4], bf[4];
#pragma unroll
                for (int i = 0; i < 4; ++i) af[i] = *(const frag16*)(lpa + i * 16 * 136 + kk * 32);
#pragma unroll
                for (int j = 0; j < 4; ++j) bf[j] = *(const frag16*)(lb + j * 16 * 64 + kk * 32);
#pragma unroll
                for (int i = 0; i < 4; ++i)
#pragma unroll
                    for (int j = 0; j < 4; ++j)
                        a2[i][j] = __builtin_amdgcn_mfma_f32_16x16x32_f16(af[i], bf[j], a2[i][j], 0, 0, 0);
            }
        }
        __syncthreads();

        float* lt = (float*)smem;   // [64][132]
#pragma unroll
        for (int h = 0; h < 2; ++h) {
            if (wn == h) {
#pragma unroll
                for (int i = 0; i < 4; ++i)
#pragma unroll
                    for (int j = 0; j < 4; ++j)
#pragma unroll
                        for (int r = 0; r < 4; ++r)
                            lt[(j * 16 + lrow) * 132 + wm * 64 + i * 16 + rbase + r] = a2[i][j][r];
            }
            __syncthreads();
#pragma unroll
            for (int it = 0; it < 32; ++it) {
                int idx = it * 256 + tid;
                int nl = idx >> 7, ml = idx & 127;
                outb[(size_t)(d0 + h * 64 + nl) * 4096 + l0 + ml] = lt[nl * 132 + ml];
            }
            __syncthreads();
        }
    }
}

// ---------------------------------------------------------------------------
extern "C" void kernel_launch(void* const* d_in, const int* in_sizes, int n_in,
                              void* d_out, int out_size, void* d_ws, size_t ws_size,
                              hipStream_t stream) {
    // B=8, D=512, L=4096, P=128, BL=32768
    const float* x  = (const float*)d_in[0];
    const float* Wq = (const float*)d_in[1];
    const float* bq = (const float*)d_in[2];
    const float* Wk = (const float*)d_in[3];
    const float* bk = (const float*)d_in[4];
    const float* Wv = (const float*)d_in[5];
    const float* bv = (const float*)d_in[6];
    float* out = (float*)d_out;

    const size_t o_xb = 0;                    // 32MB f16 [32768][512]
    const size_t o_qk = 33554432;             // 64MB f16 [32768][1024] (q cols 0-511, k cols 512-1023)
    const size_t o_vT = 100663296;            // 32MB f16 [8][512][4096]
    const size_t o_w  = 134217728;            // wqkv f16 [1536][512], 1.5MB
    const size_t o_ab = o_w + 1572864;        // a f16 [8][128][512], 1MB
    const size_t o_cT = o_ab + 1048576;       // cT f16 [8][512][128], 1MB
    const size_t o_S  = o_cT + 1048576;       // scores fp32 16MB (S1, then PV partials)
    const size_t o_P  = o_S + 16777216;       // probs f16, 8MB (P1)
    const size_t need = o_P + 8388608;        // ~155.5 MB
    if (ws_size < need) return;

    char* ws = (char*)d_ws;
    f16* xb   = (f16*)(ws + o_xb);
    f16* qk   = (f16*)(ws + o_qk);
    f16* vT   = (f16*)(ws + o_vT);
    f16* wqkv = (f16*)(ws + o_w);
    f16* ab   = (f16*)(ws + o_ab);
    f16* cT   = (f16*)(ws + o_cT);
    float* Sb = (float*)(ws + o_S);
    float* Pp = (float*)(ws + o_S);           // PV partials alias S (disjoint lifetime)
    f16* Pb   = (f16*)(ws + o_P);

    // 1. weights fp32 -> f16 packed [Wq;Wk;Wv], one launch
    cvt3_f16<<<3072, 256, 0, stream>>>(Wq, Wk, Wv, wqkv);

    // 2. x [B][D][L] -> xb [B][L][D] f16
    transpose_f32_f16<<<dim3(8, 64, 8), 256, 0, stream>>>(x, xb);

    // 3. fused QKV projection (M=32768, N=1536, K=512) + fused avg-pool -> ab
    //    XCD-grouped grid: x = XCD slot (8), y = n-tile (12), z = m-chunk (32)
    gemm_qkv<<<dim3(8, 12, 32), 512, 0, stream>>>(xb, wqkv, bq, bk, bv, qk, vT, ab);

    // 4. stage-1 scores: S1[b][p][l] = a . k  (M=128,N=4096,K=512)
    gemm_lds<false, false, false><<<dim3(1, 32, 8), 256, 0, stream>>>(
        ab, qk + 512, nullptr, Sb, 512, 512, 1024, 4096, 65536LL, 4194304LL, 524288LL, 1);

    // 5. softmax over l -> P1 f16
    softmax4096<<<1024, 256, 0, stream>>>(Sb, Pb);

    // 6. PV split-K partials: Pp[b*8+s][p][d] (M=128,N=512,K=4096,splitk=8)
    gemm_lds<false, false, false><<<dim3(1, 4, 64), 256, 0, stream>>>(
        Pb, vT, nullptr, Pp, 4096, 4096, 4096, 512, 524288LL, 2097152LL, 65536LL, 8);
    // 6r. reduce + transpose -> cT[b][d][p] f16
    reduce_pv<<<2048, 256, 0, stream>>>(Pp, cT);

    // 7. fused stage-2: S2 -> softmax -> P2.cT^T -> out[b][d][l]
    attn2<<<dim3(32, 8), 256, 0, stream>>>(qk, ab, cT, out);
}

// Round 15
// 191.503 us; speedup vs baseline: 1.0534x; 1.0534x over previous
//
#include <hip/hip_runtime.h>
#include <hip/hip_fp16.h>

typedef _Float16 f16;
using frag16 = __attribute__((ext_vector_type(8))) _Float16;  // 8 f16 (4 VGPRs)
using f32x4  = __attribute__((ext_vector_type(4))) float;     // MFMA accumulator

// async global->LDS, 16B per lane.
__device__ __forceinline__ void gload_lds16(const void* g, void* l) {
    __builtin_amdgcn_global_load_lds(
        (const __attribute__((address_space(1))) void*)g,
        (__attribute__((address_space(3))) void*)l, 16, 0, 0);
}

// ---------------------------------------------------------------------------
// fp32 -> f16 convert for all three weight matrices in one launch.
__global__ __launch_bounds__(256) void cvt3_f16(const float* __restrict__ Wq,
                                                const float* __restrict__ Wk,
                                                const float* __restrict__ Wv,
                                                f16* __restrict__ out) {
    int i = blockIdx.x * 256 + threadIdx.x;     // 0..786431
    const float* src = (i < 262144) ? Wq : (i < 524288) ? Wk : Wv;
    out[i] = (f16)src[i & 262143];
}

// ---------------------------------------------------------------------------
// x [B][512][4096] fp32 -> xb [B][4096][512] f16  (64x64 LDS tile)
__global__ __launch_bounds__(256) void transpose_f32_f16(const float* __restrict__ in,
                                                         f16* __restrict__ out) {
    __shared__ float t[64][65];
    const int b = blockIdx.z;
    const int d0 = blockIdx.x * 64, l0 = blockIdx.y * 64;
    const float* ip = in + (size_t)b * 512 * 4096;
    f16* op = out + (size_t)b * 4096 * 512;
    const int tx = threadIdx.x & 63, ty = threadIdx.x >> 6;
#pragma unroll
    for (int r = 0; r < 16; ++r) {
        int d = r * 4 + ty;
        t[d][tx] = ip[(size_t)(d0 + d) * 4096 + l0 + tx];
    }
    __syncthreads();
#pragma unroll
    for (int it = 0; it < 4; ++it) {
        int idx = it * 256 + threadIdx.x;
        int l = idx >> 4, dq = (idx & 15) * 4;
        union { f16 h[4]; unsigned long long u; } pk;
        pk.h[0] = (f16)t[dq + 0][l];
        pk.h[1] = (f16)t[dq + 1][l];
        pk.h[2] = (f16)t[dq + 2][l];
        pk.h[3] = (f16)t[dq + 3][l];
        *reinterpret_cast<unsigned long long*>(&op[(size_t)(l0 + l) * 512 + d0 + dq]) = pk.u;
    }
}

// ---------------------------------------------------------------------------
// row softmax, len=4096: fp32 in -> f16 probs. one block (256 thr) per row
__global__ __launch_bounds__(256) void softmax4096(const float* __restrict__ S,
                                                   f16* __restrict__ P) {
    const float* s = S + (size_t)blockIdx.x * 4096;
    f16* p = P + (size_t)blockIdx.x * 4096;
    const int tid = threadIdx.x;
    float v[16];
    float mx = -3.0e38f;
#pragma unroll
    for (int i = 0; i < 16; ++i) { v[i] = s[i * 256 + tid]; mx = fmaxf(mx, v[i]); }
#pragma unroll
    for (int o = 32; o; o >>= 1) mx = fmaxf(mx, __shfl_xor(mx, o));
    __shared__ float redm[4];
    __shared__ float reds[4];
    if ((tid & 63) == 0) redm[tid >> 6] = mx;
    __syncthreads();
    mx = fmaxf(fmaxf(redm[0], redm[1]), fmaxf(redm[2], redm[3]));
    float sum = 0.f;
#pragma unroll
    for (int i = 0; i < 16; ++i) { v[i] = __expf(v[i] - mx); sum += v[i]; }
#pragma unroll
    for (int o = 32; o; o >>= 1) sum += __shfl_xor(sum, o);
    if ((tid & 63) == 0) reds[tid >> 6] = sum;
    __syncthreads();
    sum = reds[0] + reds[1] + reds[2] + reds[3];
    float inv = 1.f / sum;
#pragma unroll
    for (int i = 0; i < 16; ++i) p[i * 256 + tid] = (f16)(v[i] * inv);
}

// ---------------------------------------------------------------------------
// Fused QKV projection — 8-wave / 512-thread, double-buffered prefetch K-loop.
// stage(t+1) issued BEFORE compute(t); vmcnt(4) waits only the current tile's
// 4 loads; raw s_barrier; never drain to 0 in the loop.
// XCD grouping in grid shape: grid dim3(8, 12, 32).
__global__ __launch_bounds__(512) void gemm_qkv(
    const f16* __restrict__ xb, const f16* __restrict__ w,
    const float* __restrict__ bq, const float* __restrict__ bk,
    const float* __restrict__ bv,
    f16* __restrict__ qk, f16* __restrict__ vT, f16* __restrict__ a)
{
    __shared__ __align__(16) char smem[65536];   // 2 x (16KB A + 16KB B); epilogue aliases
    const int tid = threadIdx.x;                 // 0..511
    const int lane = tid & 63, wave = tid >> 6;  // 8 waves
    const int wm = wave >> 2, wn = wave & 3;     // 2m x 4n

    const int m0b = ((blockIdx.z << 3) + blockIdx.x) << 7;   // m_tile*128
    const int n0b = blockIdx.y << 7;                          // n_tile*128

    const int lrow = lane & 15, kgrp = (lane >> 4) * 8;

    // staging: 512 threads cover 1024 chunks of 16B per matrix (2 each)
    const int tr = tid >> 3, tc = (tid & 7) * 8;  // rows 0-63; +64 for chunk 2
    const f16* gA = xb + (size_t)(m0b + tr) * 512 + tc;
    const f16* gB = w  + (size_t)(n0b + tr) * 512 + tc;

    f32x4 acc[4][2] = {};

    auto stage = [&](int bi, int k0) {
        char* sAp = smem + bi * 32768 + tid * 16;
        char* sBp = sAp + 16384;
        gload_lds16(gA + k0,                     sAp);
        gload_lds16(gA + (size_t)64 * 512 + k0,  sAp + 8192);
        gload_lds16(gB + k0,                     sBp);
        gload_lds16(gB + (size_t)64 * 512 + k0,  sBp + 8192);
    };
    auto compute = [&](int bi) {
        const f16* la = (const f16*)(smem + bi * 32768) + (wm * 64 + lrow) * 64 + kgrp;
        const f16* lb = (const f16*)(smem + bi * 32768 + 16384) + (wn * 32 + lrow) * 64 + kgrp;
#pragma unroll
        for (int kk = 0; kk < 2; ++kk) {
            frag16 af[4], bf[2];
#pragma unroll
            for (int i = 0; i < 4; ++i) af[i] = *(const frag16*)(la + i * 16 * 64 + kk * 32);
#pragma unroll
            for (int j = 0; j < 2; ++j) bf[j] = *(const frag16*)(lb + j * 16 * 64 + kk * 32);
#pragma unroll
            for (int i = 0; i < 4; ++i)
#pragma unroll
                for (int j = 0; j < 2; ++j)
                    acc[i][j] = __builtin_amdgcn_mfma_f32_16x16x32_f16(af[i], bf[j], acc[i][j], 0, 0, 0);
        }
    };

    stage(0, 0);
    int cur = 0;
#pragma unroll 1
    for (int t = 0; t < 7; ++t) {
        stage(cur ^ 1, (t + 1) * 64);                      // prefetch next tile
        asm volatile("s_waitcnt vmcnt(4)" ::: "memory");   // wait current tile only
        __builtin_amdgcn_s_barrier();
        __builtin_amdgcn_sched_barrier(0);
        compute(cur);
        __builtin_amdgcn_s_barrier();                      // readers done before overwrite
        cur ^= 1;
    }
    asm volatile("s_waitcnt vmcnt(0)" ::: "memory");
    __builtin_amdgcn_s_barrier();
    __builtin_amdgcn_sched_barrier(0);
    compute(cur);
    __builtin_amdgcn_s_barrier();                          // before epilogue reuses smem

    const int rbase = (lane >> 4) * 4;
    if (n0b < 1024) {
        const float* bptr = (n0b < 512) ? bq : bk;

        // fused AdaptiveAvgPool (q-part only): wave rows wm*64..+63 cover
        // pool groups pbase (i=0,1) and pbase+1 (i=2,3)
        if (n0b < 512) {
            const int b = m0b >> 12;
            const int pbase = ((m0b & 4095) >> 5) + wm * 2;
#pragma unroll
            for (int j = 0; j < 2; ++j) {
                int d = n0b + wn * 32 + j * 16 + lrow;
                float badd = bptr[d];
                float s0 = 0.f, s1 = 0.f;
#pragma unroll
                for (int r = 0; r < 4; ++r) {
                    s0 += acc[0][j][r] + acc[1][j][r];
                    s1 += acc[2][j][r] + acc[3][j][r];
                }
                s0 += __shfl_xor(s0, 16); s0 += __shfl_xor(s0, 32);
                s1 += __shfl_xor(s1, 16); s1 += __shfl_xor(s1, 32);
                if (lane < 16) {
                    a[((size_t)(b * 128 + pbase)     * 512) + d] = (f16)(s0 * 0.03125f + badd);
                    a[((size_t)(b * 128 + pbase + 1) * 512) + d] = (f16)(s1 * 0.03125f + badd);
                }
            }
        }

        // coalesced qk store via LDS staging: f16 tile [128][136]
        f16* lt = (f16*)smem;
#pragma unroll
        for (int j = 0; j < 2; ++j) {
            int col = wn * 32 + j * 16 + lrow;
            float badd = bptr[(n0b + col) & 511];
#pragma unroll
            for (int i = 0; i < 4; ++i) {
                int row = wm * 64 + i * 16 + rbase;
#pragma unroll
                for (int r = 0; r < 4; ++r)
                    lt[(row + r) * 136 + col] = (f16)(acc[i][j][r] + badd);
            }
        }
        __syncthreads();
#pragma unroll
        for (int it = 0; it < 4; ++it) {
            int cu = it * 512 + tid;            // 2048 chunks of 8 f16
            int row = cu >> 4, c8 = (cu & 15) * 8;
            *reinterpret_cast<uint4*>(&qk[(size_t)(m0b + row) * 1024 + n0b + c8]) =
                *reinterpret_cast<const uint4*>(&lt[row * 136 + c8]);
        }
    } else {
        const int b = m0b >> 12, l0 = m0b & 4095;
        const int d0 = n0b - 1024;
        f16* vout = vT + (size_t)b * 2097152 + l0;
        float* lt = (float*)smem;   // [64][132] fp32
#pragma unroll
        for (int h = 0; h < 2; ++h) {
            if ((wn >> 1) == h) {
#pragma unroll
                for (int i = 0; i < 4; ++i)
#pragma unroll
                    for (int j = 0; j < 2; ++j)
#pragma unroll
                        for (int r = 0; r < 4; ++r)
                            lt[((wn & 1) * 32 + j * 16 + lrow) * 132 + wm * 64 + i * 16 + rbase + r]
                                = acc[i][j][r];
            }
            __syncthreads();
#pragma unroll
            for (int it = 0; it < 16; ++it) {
                int idx = it * 512 + tid;       // 8192 = 64 x 128
                int nl = idx >> 7, ml = idx & 127;
                int d = d0 + h * 64 + nl;
                float val = lt[nl * 132 + ml] + bv[d];
                vout[(size_t)d * 4096 + ml] = (f16)val;
            }
            __syncthreads();
        }
    }
}

// ---------------------------------------------------------------------------
// Generic NT GEMM with the prefetched double-buffer K-loop.
// NOTE: gA/gB do NOT include kbeg — stage() receives the absolute k offset
// (R14's bug was kbeg added in both places, corrupting splitk>1 calls).
template<bool OUT_F16, bool BIAS, bool TRANS_OUT>
__global__ __launch_bounds__(256) void gemm_lds(
    const f16* __restrict__ A, const f16* __restrict__ B,
    const float* __restrict__ bias, void* __restrict__ C,
    int K, int lda, int ldb, int ldc,
    long long sA, long long sB, long long sC, int splitk)
{
    __shared__ __align__(16) char smem[65536];
    const int z = blockIdx.z;
    const int batch = z / splitk;
    const int ks = z - batch * splitk;
    const int Ksub = K / splitk;
    const int kbeg = ks * Ksub;

    const f16* Ab = A + (size_t)batch * sA;
    const f16* Bb = B + (size_t)batch * sB;

    const int tid = threadIdx.x;
    const int lane = tid & 63, wave = tid >> 6;
    const int wm = wave >> 1, wn = wave & 1;
    const int m0b = blockIdx.x * 128, n0b = blockIdx.y * 128;
    const int lrow = lane & 15, kgrp = (lane >> 4) * 8;

    const int tr = tid >> 3, tc = (tid & 7) * 8;
    const f16* gA = Ab + (size_t)(m0b + tr) * lda + tc;   // no kbeg here!
    const f16* gB = Bb + (size_t)(n0b + tr) * ldb + tc;   // no kbeg here!

    f32x4 acc[4][4] = {};

    auto stage = [&](int bi, int k0) {
        char* sAp = smem + bi * 32768 + tid * 16;
        char* sBp = sAp + 16384;
#pragma unroll
        for (int i = 0; i < 4; ++i) {
            gload_lds16(gA + (size_t)(i * 32) * lda + k0, sAp + i * 4096);
            gload_lds16(gB + (size_t)(i * 32) * ldb + k0, sBp + i * 4096);
        }
    };
    auto compute = [&](int bi) {
        const f16* la = (const f16*)(smem + bi * 32768) + (wm * 64 + lrow) * 64 + kgrp;
        const f16* lb = (const f16*)(smem + bi * 32768 + 16384) + (wn * 64 + lrow) * 64 + kgrp;
#pragma unroll
        for (int kk = 0; kk < 2; ++kk) {
            frag16 af[4], bf[4];
#pragma unroll
            for (int i = 0; i < 4; ++i) af[i] = *(const frag16*)(la + i * 16 * 64 + kk * 32);
#pragma unroll
            for (int j = 0; j < 4; ++j) bf[j] = *(const frag16*)(lb + j * 16 * 64 + kk * 32);
#pragma unroll
            for (int i = 0; i < 4; ++i)
#pragma unroll
                for (int j = 0; j < 4; ++j)
                    acc[i][j] = __builtin_amdgcn_mfma_f32_16x16x32_f16(af[i], bf[j], acc[i][j], 0, 0, 0);
        }
    };

    stage(0, kbeg);
    int cur = 0;
    const int nt = Ksub >> 6;
#pragma unroll 1
    for (int t = 0; t < nt - 1; ++t) {
        stage(cur ^ 1, kbeg + (t + 1) * 64);
        asm volatile("s_waitcnt vmcnt(8)" ::: "memory");
        __builtin_amdgcn_s_barrier();
        __builtin_amdgcn_sched_barrier(0);
        compute(cur);
        __builtin_amdgcn_s_barrier();
        cur ^= 1;
    }
    asm volatile("s_waitcnt vmcnt(0)" ::: "memory");
    __builtin_amdgcn_s_barrier();
    __builtin_amdgcn_sched_barrier(0);
    compute(cur);
    __builtin_amdgcn_s_barrier();

    const int rbase = (lane >> 4) * 4;
    const size_t cb = (size_t)z * sC;
    if constexpr (TRANS_OUT) {
        float* lt = (float*)smem;   // [64][132]
#pragma unroll
        for (int h = 0; h < 2; ++h) {
            if (wn == h) {
#pragma unroll
                for (int i = 0; i < 4; ++i)
#pragma unroll
                    for (int j = 0; j < 4; ++j)
#pragma unroll
                        for (int r = 0; r < 4; ++r)
                            lt[(j * 16 + lrow) * 132 + wm * 64 + i * 16 + rbase + r] = acc[i][j][r];
            }
            __syncthreads();
#pragma unroll
            for (int it = 0; it < 32; ++it) {
                int idx = it * 256 + tid;
                int nl = idx >> 7, ml = idx & 127;
                int n = n0b + h * 64 + nl;
                float val = lt[nl * 132 + ml] + (BIAS ? bias[n] : 0.f);
                size_t o = cb + (size_t)n * ldc + m0b + ml;
                if constexpr (OUT_F16) ((f16*)C)[o] = (f16)val;
                else                   ((float*)C)[o] = val;
            }
            __syncthreads();
        }
    } else {
#pragma unroll
        for (int j = 0; j < 4; ++j) {
            int col = n0b + wn * 64 + j * 16 + lrow;
            float badd = BIAS ? bias[col] : 0.f;
#pragma unroll
            for (int i = 0; i < 4; ++i) {
                int row = m0b + wm * 64 + i * 16 + rbase;
#pragma unroll
                for (int r = 0; r < 4; ++r) {
                    float val = acc[i][j][r] + badd;
                    size_t o = cb + (size_t)(row + r) * ldc + col;
                    if constexpr (OUT_F16) ((f16*)C)[o] = (f16)val;
                    else                   ((float*)C)[o] = val;
                }
            }
        }
    }
}

// ---------------------------------------------------------------------------
// split-K reduce for PV: cT[b][d][p] = sum_{s<8} Pp[b*8+s][p][d], fp32 -> f16
__global__ __launch_bounds__(256) void reduce_pv(const float* __restrict__ Pp,
                                                 f16* __restrict__ cT) {
    int idx = blockIdx.x * 256 + threadIdx.x;   // 524288 total
    int d = idx & 511, p = (idx >> 9) & 127, b = idx >> 16;
    float s = 0.f;
#pragma unroll
    for (int k = 0; k < 8; ++k)
        s += Pp[(size_t)(b * 8 + k) * 65536 + p * 512 + d];
    cT[(size_t)b * 65536 + d * 128 + p] = (f16)s;
}

// ---------------------------------------------------------------------------
// Fused stage-2: S2 = q.a^T -> in-register softmax -> P2 (f16 LDS) ->
// r = P2.cT^T -> transposed fp32 store to out[b][d][l]. grid dim3(32, 8).
__global__ __launch_bounds__(256) void attn2(
    const f16* __restrict__ qk, const f16* __restrict__ ab,
    const f16* __restrict__ cT, float* __restrict__ out)
{
    __shared__ __align__(16) char smem[69632];
    float* scr = (float*)(smem + 33280);
    f16*   P2  = (f16*)(smem + 34816);

    const int tid = threadIdx.x;
    const int lane = tid & 63, wave = tid >> 6;
    const int wm = wave >> 1, wn = wave & 1;
    const int l0 = blockIdx.x * 128;
    const int b  = blockIdx.y;
    const int lrow = lane & 15, kgrp = (lane >> 4) * 8, rbase = (lane >> 4) * 4;
    const int tr = tid >> 3, tc = (tid & 7) * 8;

    char* sAp = smem + tid * 16;
    char* sBp = smem + 16384 + tid * 16;

    // ---- phase 1: S2 tile = q . a^T ----
    const f16* gA = qk + (size_t)b * 4194304 + (size_t)(l0 + tr) * 1024 + tc;
    const f16* gB = ab + (size_t)b * 65536  + (size_t)tr * 512 + tc;

    f32x4 acc[4][4] = {};
#pragma unroll 1
    for (int k0 = 0; k0 < 512; k0 += 64) {
#pragma unroll
        for (int i = 0; i < 4; ++i) {
            gload_lds16(gA + (size_t)(i * 32) * 1024 + k0, sAp + i * 4096);
            gload_lds16(gB + (size_t)(i * 32) * 512  + k0, sBp + i * 4096);
        }
        __syncthreads();
        const f16* la = (const f16*)smem + (wm * 64 + lrow) * 64 + kgrp;
        const f16* lb = (const f16*)(smem + 16384) + (wn * 64 + lrow) * 64 + kgrp;
#pragma unroll
        for (int kk = 0; kk < 2; ++kk) {
            frag16 af[4], bf[4];
#pragma unroll
            for (int i = 0; i < 4; ++i) af[i] = *(const frag16*)(la + i * 16 * 64 + kk * 32);
#pragma unroll
            for (int j = 0; j < 4; ++j) bf[j] = *(const frag16*)(lb + j * 16 * 64 + kk * 32);
#pragma unroll
            for (int i = 0; i < 4; ++i)
#pragma unroll
                for (int j = 0; j < 4; ++j)
                    acc[i][j] = __builtin_amdgcn_mfma_f32_16x16x32_f16(af[i], bf[j], acc[i][j], 0, 0, 0);
        }
        __syncthreads();
    }

    // ---- phase 2: softmax over N=128 (p), rows are l ----
    float mx[4][4];
#pragma unroll
    for (int i = 0; i < 4; ++i)
#pragma unroll
        for (int r = 0; r < 4; ++r) {
            float m = fmaxf(fmaxf(acc[i][0][r], acc[i][1][r]),
                            fmaxf(acc[i][2][r], acc[i][3][r]));
            m = fmaxf(m, __shfl_xor(m, 1));
            m = fmaxf(m, __shfl_xor(m, 2));
            m = fmaxf(m, __shfl_xor(m, 4));
            m = fmaxf(m, __shfl_xor(m, 8));
            mx[i][r] = m;
        }
    if ((lane & 15) == 0) {
#pragma unroll
        for (int i = 0; i < 4; ++i)
#pragma unroll
            for (int r = 0; r < 4; ++r)
                scr[wn * 128 + wm * 64 + i * 16 + rbase + r] = mx[i][r];
    }
    __syncthreads();
    float rowm[4][4];
#pragma unroll
    for (int i = 0; i < 4; ++i)
#pragma unroll
        for (int r = 0; r < 4; ++r) {
            int row = wm * 64 + i * 16 + rbase + r;
            rowm[i][r] = fmaxf(scr[row], scr[128 + row]);
        }
    __syncthreads();
    float sum[4][4];
#pragma unroll
    for (int i = 0; i < 4; ++i)
#pragma unroll
        for (int r = 0; r < 4; ++r) {
            float s = 0.f;
#pragma unroll
            for (int j = 0; j < 4; ++j) {
                float p = __expf(acc[i][j][r] - rowm[i][r]);
                acc[i][j][r] = p;
                s += p;
            }
            s += __shfl_xor(s, 1);
            s += __shfl_xor(s, 2);
            s += __shfl_xor(s, 4);
            s += __shfl_xor(s, 8);
            sum[i][r] = s;
        }
    if ((lane & 15) == 0) {
#pragma unroll
        for (int i = 0; i < 4; ++i)
#pragma unroll
            for (int r = 0; r < 4; ++r)
                scr[wn * 128 + wm * 64 + i * 16 + rbase + r] = sum[i][r];
    }
    __syncthreads();
#pragma unroll
    for (int i = 0; i < 4; ++i)
#pragma unroll
        for (int r = 0; r < 4; ++r) {
            int row = wm * 64 + i * 16 + rbase + r;
            float inv = 1.f / (scr[row] + scr[128 + row]);
#pragma unroll
            for (int j = 0; j < 4; ++j)
                P2[row * 136 + wn * 64 + j * 16 + lrow] = (f16)(acc[i][j][r] * inv);
        }
    __syncthreads();

    // ---- phase 3: r = P2 . cT^T, 4 chunks of 128 d-cols, K=128 (p) ----
    const f16* gC = cT + (size_t)b * 65536;
    float* outb = out + (size_t)b * 512 * 4096;
#pragma unroll 1
    for (int c = 0; c < 4; ++c) {
        const int d0 = c * 128;
#pragma unroll
        for (int i = 0; i < 4; ++i) {
            gload_lds16(gC + (size_t)(d0 + tr + i * 32) * 128 + tc,      sAp + i * 4096);
            gload_lds16(gC + (size_t)(d0 + tr + i * 32) * 128 + tc + 64, sBp + i * 4096);
        }
        __syncthreads();
        f32x4 a2[4][4] = {};
#pragma unroll
        for (int half = 0; half < 2; ++half) {
            const f16* lb = (const f16*)(smem + half * 16384) + (wn * 64 + lrow) * 64 + kgrp;
            const f16* lpa = P2 + (wm * 64 + lrow) * 136 + half * 64 + kgrp;
#pragma unroll
            for (int kk = 0; kk < 2; ++kk) {
                frag16 af[4], bf[4];
#pragma unroll
                for (int i = 0; i < 4; ++i) af[i] = *(const frag16*)(lpa + i * 16 * 136 + kk * 32);
#pragma unroll
                for (int j = 0; j < 4; ++j) bf[j] = *(const frag16*)(lb + j * 16 * 64 + kk * 32);
#pragma unroll
                for (int i = 0; i < 4; ++i)
#pragma unroll
                    for (int j = 0; j < 4; ++j)
                        a2[i][j] = __builtin_amdgcn_mfma_f32_16x16x32_f16(af[i], bf[j], a2[i][j], 0, 0, 0);
            }
        }
        __syncthreads();

        float* lt = (float*)smem;   // [64][132]
#pragma unroll
        for (int h = 0; h < 2; ++h) {
            if (wn == h) {
#pragma unroll
                for (int i = 0; i < 4; ++i)
#pragma unroll
                    for (int j = 0; j < 4; ++j)
#pragma unroll
                        for (int r = 0; r < 4; ++r)
                            lt[(j * 16 + lrow) * 132 + wm * 64 + i * 16 + rbase + r] = a2[i][j][r];
            }
            __syncthreads();
#pragma unroll
            for (int it = 0; it < 32; ++it) {
                int idx = it * 256 + tid;
                int nl = idx >> 7, ml = idx & 127;
                outb[(size_t)(d0 + h * 64 + nl) * 4096 + l0 + ml] = lt[nl * 132 + ml];
            }
            __syncthreads();
        }
    }
}

// ---------------------------------------------------------------------------
extern "C" void kernel_launch(void* const* d_in, const int* in_sizes, int n_in,
                              void* d_out, int out_size, void* d_ws, size_t ws_size,
                              hipStream_t stream) {
    // B=8, D=512, L=4096, P=128, BL=32768
    const float* x  = (const float*)d_in[0];
    const float* Wq = (const float*)d_in[1];
    const float* bq = (const float*)d_in[2];
    const float* Wk = (const float*)d_in[3];
    const float* bk = (const float*)d_in[4];
    const float* Wv = (const float*)d_in[5];
    const float* bv = (const float*)d_in[6];
    float* out = (float*)d_out;

    const size_t o_xb = 0;                    // 32MB f16 [32768][512]
    const size_t o_qk = 33554432;             // 64MB f16 [32768][1024] (q cols 0-511, k cols 512-1023)
    const size_t o_vT = 100663296;            // 32MB f16 [8][512][4096]
    const size_t o_w  = 134217728;            // wqkv f16 [1536][512], 1.5MB
    const size_t o_ab = o_w + 1572864;        // a f16 [8][128][512], 1MB
    const size_t o_cT = o_ab + 1048576;       // cT f16 [8][512][128], 1MB
    const size_t o_S  = o_cT + 1048576;       // scores fp32 16MB (S1, then PV partials)
    const size_t o_P  = o_S + 16777216;       // probs f16, 8MB (P1)
    const size_t need = o_P + 8388608;        // ~155.5 MB
    if (ws_size < need) return;

    char* ws = (char*)d_ws;
    f16* xb   = (f16*)(ws + o_xb);
    f16* qk   = (f16*)(ws + o_qk);
    f16* vT   = (f16*)(ws + o_vT);
    f16* wqkv = (f16*)(ws + o_w);
    f16* ab   = (f16*)(ws + o_ab);
    f16* cT   = (f16*)(ws + o_cT);
    float* Sb = (float*)(ws + o_S);
    float* Pp = (float*)(ws + o_S);           // PV partials alias S (disjoint lifetime)
    f16* Pb   = (f16*)(ws + o_P);

    // 1. weights fp32 -> f16 packed [Wq;Wk;Wv], one launch
    cvt3_f16<<<3072, 256, 0, stream>>>(Wq, Wk, Wv, wqkv);

    // 2. x [B][D][L] -> xb [B][L][D] f16
    transpose_f32_f16<<<dim3(8, 64, 8), 256, 0, stream>>>(x, xb);

    // 3. fused QKV projection (M=32768, N=1536, K=512) + fused avg-pool -> ab
    //    XCD-grouped grid: x = XCD slot (8), y = n-tile (12), z = m-chunk (32)
    gemm_qkv<<<dim3(8, 12, 32), 512, 0, stream>>>(xb, wqkv, bq, bk, bv, qk, vT, ab);

    // 4. stage-1 scores: S1[b][p][l] = a . k  (M=128,N=4096,K=512)
    gemm_lds<false, false, false><<<dim3(1, 32, 8), 256, 0, stream>>>(
        ab, qk + 512, nullptr, Sb, 512, 512, 1024, 4096, 65536LL, 4194304LL, 524288LL, 1);

    // 5. softmax over l -> P1 f16
    softmax4096<<<1024, 256, 0, stream>>>(Sb, Pb);

    // 6. PV split-K partials: Pp[b*8+s][p][d] (M=128,N=512,K=4096,splitk=8)
    gemm_lds<false, false, false><<<dim3(1, 4, 64), 256, 0, stream>>>(
        Pb, vT, nullptr, Pp, 4096, 4096, 4096, 512, 524288LL, 2097152LL, 65536LL, 8);
    // 6r. reduce + transpose -> cT[b][d][p] f16
    reduce_pv<<<2048, 256, 0, stream>>>(Pp, cT);

    // 7. fused stage-2: S2 -> softmax -> P2.cT^T -> out[b][d][l]
    attn2<<<dim3(32, 8), 256, 0, stream>>>(qk, ab, cT, out);
}

// Round 16
// 164.374 us; speedup vs baseline: 1.2273x; 1.1650x over previous
//
#include <hip/hip_runtime.h>
#include <hip/hip_fp16.h>

typedef _Float16 f16;
using frag16 = __attribute__((ext_vector_type(8))) _Float16;  // 8 f16 (4 VGPRs)
using f32x4  = __attribute__((ext_vector_type(4))) float;     // MFMA accumulator

// async global->LDS, 16B per lane.
__device__ __forceinline__ void gload_lds16(const void* g, void* l) {
    __builtin_amdgcn_global_load_lds(
        (const __attribute__((address_space(1))) void*)g,
        (__attribute__((address_space(3))) void*)l, 16, 0, 0);
}

// ---------------------------------------------------------------------------
// fp32 -> f16 convert for all three weight matrices in one launch.
__global__ __launch_bounds__(256) void cvt3_f16(const float* __restrict__ Wq,
                                                const float* __restrict__ Wk,
                                                const float* __restrict__ Wv,
                                                f16* __restrict__ out) {
    int i = blockIdx.x * 256 + threadIdx.x;     // 0..786431
    const float* src = (i < 262144) ? Wq : (i < 524288) ? Wk : Wv;
    out[i] = (f16)src[i & 262143];
}

// ---------------------------------------------------------------------------
// x [B][512][4096] fp32 -> xb [B][4096][512] f16  (64x64 LDS tile)
__global__ __launch_bounds__(256) void transpose_f32_f16(const float* __restrict__ in,
                                                         f16* __restrict__ out) {
    __shared__ float t[64][65];
    const int b = blockIdx.z;
    const int d0 = blockIdx.x * 64, l0 = blockIdx.y * 64;
    const float* ip = in + (size_t)b * 512 * 4096;
    f16* op = out + (size_t)b * 4096 * 512;
    const int tx = threadIdx.x & 63, ty = threadIdx.x >> 6;
#pragma unroll
    for (int r = 0; r < 16; ++r) {
        int d = r * 4 + ty;
        t[d][tx] = ip[(size_t)(d0 + d) * 4096 + l0 + tx];
    }
    __syncthreads();
#pragma unroll
    for (int it = 0; it < 4; ++it) {
        int idx = it * 256 + threadIdx.x;
        int l = idx >> 4, dq = (idx & 15) * 4;
        union { f16 h[4]; unsigned long long u; } pk;
        pk.h[0] = (f16)t[dq + 0][l];
        pk.h[1] = (f16)t[dq + 1][l];
        pk.h[2] = (f16)t[dq + 2][l];
        pk.h[3] = (f16)t[dq + 3][l];
        *reinterpret_cast<unsigned long long*>(&op[(size_t)(l0 + l) * 512 + d0 + dq]) = pk.u;
    }
}

// ---------------------------------------------------------------------------
// row softmax, len=4096: fp32 in -> f16 probs. one block (256 thr) per row
__global__ __launch_bounds__(256) void softmax4096(const float* __restrict__ S,
                                                   f16* __restrict__ P) {
    const float* s = S + (size_t)blockIdx.x * 4096;
    f16* p = P + (size_t)blockIdx.x * 4096;
    const int tid = threadIdx.x;
    float v[16];
    float mx = -3.0e38f;
#pragma unroll
    for (int i = 0; i < 16; ++i) { v[i] = s[i * 256 + tid]; mx = fmaxf(mx, v[i]); }
#pragma unroll
    for (int o = 32; o; o >>= 1) mx = fmaxf(mx, __shfl_xor(mx, o));
    __shared__ float redm[4];
    __shared__ float reds[4];
    if ((tid & 63) == 0) redm[tid >> 6] = mx;
    __syncthreads();
    mx = fmaxf(fmaxf(redm[0], redm[1]), fmaxf(redm[2], redm[3]));
    float sum = 0.f;
#pragma unroll
    for (int i = 0; i < 16; ++i) { v[i] = __expf(v[i] - mx); sum += v[i]; }
#pragma unroll
    for (int o = 32; o; o >>= 1) sum += __shfl_xor(sum, o);
    if ((tid & 63) == 0) reds[tid >> 6] = sum;
    __syncthreads();
    sum = reds[0] + reds[1] + reds[2] + reds[3];
    float inv = 1.f / sum;
#pragma unroll
    for (int i = 0; i < 16; ++i) p[i * 256 + tid] = (f16)(v[i] * inv);
}

// ---------------------------------------------------------------------------
// Fused QKV projection — 8-wave / 512-thread, double-buffered prefetch K-loop
// + T2 LDS XOR-swizzle (rule #21: linear gload_lds dest, pre-swizzled global
// SOURCE chunk (t&7)^(tr&7), swizzled READ col ^((lrow&7)<<4)).
// The [*][64]f16 tiles have 128B row stride -> unswizzled ds_read_b128 was a
// 16-way bank conflict (28.6M/dispatch), exposed once counted-vmcnt prefetch
// removed the stage drain from the critical path.
// XCD grouping in grid shape: grid dim3(8, 12, 32).
__global__ __launch_bounds__(512) void gemm_qkv(
    const f16* __restrict__ xb, const f16* __restrict__ w,
    const float* __restrict__ bq, const float* __restrict__ bk,
    const float* __restrict__ bv,
    f16* __restrict__ qk, f16* __restrict__ vT, f16* __restrict__ a)
{
    __shared__ __align__(16) char smem[65536];   // 2 x (16KB A + 16KB B); epilogue aliases
    const int tid = threadIdx.x;                 // 0..511
    const int lane = tid & 63, wave = tid >> 6;  // 8 waves
    const int wm = wave >> 2, wn = wave & 3;     // 2m x 4n

    const int m0b = ((blockIdx.z << 3) + blockIdx.x) << 7;   // m_tile*128
    const int n0b = blockIdx.y << 7;                          // n_tile*128

    const int lrow = lane & 15, kgrp = (lane >> 4) * 8;

    // staging: thread t covers rows tr, tr+64; SOURCE chunk pre-swizzled
    const int tr = tid >> 3;
    const int tcs = (((tid & 7) ^ (tr & 7)) * 8);   // swizzled f16 col
    const f16* gA = xb + (size_t)(m0b + tr) * 512 + tcs;
    const f16* gB = w  + (size_t)(n0b + tr) * 512 + tcs;

    f32x4 acc[4][2] = {};

    auto stage = [&](int bi, int k0) {
        char* sAp = smem + bi * 32768 + tid * 16;
        char* sBp = sAp + 16384;
        gload_lds16(gA + k0,                     sAp);
        gload_lds16(gA + (size_t)64 * 512 + k0,  sAp + 8192);   // (tr+64)&7 == tr&7
        gload_lds16(gB + k0,                     sBp);
        gload_lds16(gB + (size_t)64 * 512 + k0,  sBp + 8192);
    };
    auto compute = [&](int bi) {
        const char* base = smem + bi * 32768;
        const int swz = (lrow & 7) << 4;
        const int arow = wm * 64 + lrow;   // + i*16 (16,64 ≡ 0 mod 8 -> row&7 == lrow&7)
        const int brow = wn * 32 + lrow;
#pragma unroll
        for (int kk = 0; kk < 2; ++kk) {
            const int colb = ((kgrp * 2) | (kk * 64)) ^ swz;   // swizzled byte col
            frag16 af[4], bf[2];
#pragma unroll
            for (int i = 0; i < 4; ++i)
                af[i] = *(const frag16*)(base + (arow + i * 16) * 128 + colb);
#pragma unroll
            for (int j = 0; j < 2; ++j)
                bf[j] = *(const frag16*)(base + 16384 + (brow + j * 16) * 128 + colb);
#pragma unroll
            for (int i = 0; i < 4; ++i)
#pragma unroll
                for (int j = 0; j < 2; ++j)
                    acc[i][j] = __builtin_amdgcn_mfma_f32_16x16x32_f16(af[i], bf[j], acc[i][j], 0, 0, 0);
        }
    };

    stage(0, 0);
    int cur = 0;
#pragma unroll 1
    for (int t = 0; t < 7; ++t) {
        stage(cur ^ 1, (t + 1) * 64);                      // prefetch next tile
        asm volatile("s_waitcnt vmcnt(4)" ::: "memory");   // wait current tile only
        __builtin_amdgcn_s_barrier();
        __builtin_amdgcn_sched_barrier(0);
        compute(cur);
        __builtin_amdgcn_s_barrier();                      // readers done before overwrite
        cur ^= 1;
    }
    asm volatile("s_waitcnt vmcnt(0)" ::: "memory");
    __builtin_amdgcn_s_barrier();
    __builtin_amdgcn_sched_barrier(0);
    compute(cur);
    __builtin_amdgcn_s_barrier();                          // before epilogue reuses smem

    const int rbase = (lane >> 4) * 4;
    if (n0b < 1024) {
        const float* bptr = (n0b < 512) ? bq : bk;

        // fused AdaptiveAvgPool (q-part only): wave rows wm*64..+63 cover
        // pool groups pbase (i=0,1) and pbase+1 (i=2,3)
        if (n0b < 512) {
            const int b = m0b >> 12;
            const int pbase = ((m0b & 4095) >> 5) + wm * 2;
#pragma unroll
            for (int j = 0; j < 2; ++j) {
                int d = n0b + wn * 32 + j * 16 + lrow;
                float badd = bptr[d];
                float s0 = 0.f, s1 = 0.f;
#pragma unroll
                for (int r = 0; r < 4; ++r) {
                    s0 += acc[0][j][r] + acc[1][j][r];
                    s1 += acc[2][j][r] + acc[3][j][r];
                }
                s0 += __shfl_xor(s0, 16); s0 += __shfl_xor(s0, 32);
                s1 += __shfl_xor(s1, 16); s1 += __shfl_xor(s1, 32);
                if (lane < 16) {
                    a[((size_t)(b * 128 + pbase)     * 512) + d] = (f16)(s0 * 0.03125f + badd);
                    a[((size_t)(b * 128 + pbase + 1) * 512) + d] = (f16)(s1 * 0.03125f + badd);
                }
            }
        }

        // coalesced qk store via LDS staging: f16 tile [128][136]
        f16* lt = (f16*)smem;
#pragma unroll
        for (int j = 0; j < 2; ++j) {
            int col = wn * 32 + j * 16 + lrow;
            float badd = bptr[(n0b + col) & 511];
#pragma unroll
            for (int i = 0; i < 4; ++i) {
                int row = wm * 64 + i * 16 + rbase;
#pragma unroll
                for (int r = 0; r < 4; ++r)
                    lt[(row + r) * 136 + col] = (f16)(acc[i][j][r] + badd);
            }
        }
        __syncthreads();
#pragma unroll
        for (int it = 0; it < 4; ++it) {
            int cu = it * 512 + tid;            // 2048 chunks of 8 f16
            int row = cu >> 4, c8 = (cu & 15) * 8;
            *reinterpret_cast<uint4*>(&qk[(size_t)(m0b + row) * 1024 + n0b + c8]) =
                *reinterpret_cast<const uint4*>(&lt[row * 136 + c8]);
        }
    } else {
        const int b = m0b >> 12, l0 = m0b & 4095;
        const int d0 = n0b - 1024;
        f16* vout = vT + (size_t)b * 2097152 + l0;
        float* lt = (float*)smem;   // [64][132] fp32
#pragma unroll
        for (int h = 0; h < 2; ++h) {
            if ((wn >> 1) == h) {
#pragma unroll
                for (int i = 0; i < 4; ++i)
#pragma unroll
                    for (int j = 0; j < 2; ++j)
#pragma unroll
                        for (int r = 0; r < 4; ++r)
                            lt[((wn & 1) * 32 + j * 16 + lrow) * 132 + wm * 64 + i * 16 + rbase + r]
                                = acc[i][j][r];
            }
            __syncthreads();
#pragma unroll
            for (int it = 0; it < 16; ++it) {
                int idx = it * 512 + tid;       // 8192 = 64 x 128
                int nl = idx >> 7, ml = idx & 127;
                int d = d0 + h * 64 + nl;
                float val = lt[nl * 132 + ml] + bv[d];
                vout[(size_t)d * 4096 + ml] = (f16)val;
            }
            __syncthreads();
        }
    }
}

// ---------------------------------------------------------------------------
// Generic NT GEMM — prefetched double-buffer K-loop + T2 swizzle (same scheme).
// gA/gB do NOT include kbeg — stage() receives the absolute k offset.
template<bool OUT_F16, bool BIAS, bool TRANS_OUT>
__global__ __launch_bounds__(256) void gemm_lds(
    const f16* __restrict__ A, const f16* __restrict__ B,
    const float* __restrict__ bias, void* __restrict__ C,
    int K, int lda, int ldb, int ldc,
    long long sA, long long sB, long long sC, int splitk)
{
    __shared__ __align__(16) char smem[65536];
    const int z = blockIdx.z;
    const int batch = z / splitk;
    const int ks = z - batch * splitk;
    const int Ksub = K / splitk;
    const int kbeg = ks * Ksub;

    const f16* Ab = A + (size_t)batch * sA;
    const f16* Bb = B + (size_t)batch * sB;

    const int tid = threadIdx.x;
    const int lane = tid & 63, wave = tid >> 6;
    const int wm = wave >> 1, wn = wave & 1;
    const int m0b = blockIdx.x * 128, n0b = blockIdx.y * 128;
    const int lrow = lane & 15, kgrp = (lane >> 4) * 8;

    const int tr = tid >> 3;
    const int tcs = (((tid & 7) ^ (tr & 7)) * 8);   // swizzled source col
    const f16* gA = Ab + (size_t)(m0b + tr) * lda + tcs;
    const f16* gB = Bb + (size_t)(n0b + tr) * ldb + tcs;

    f32x4 acc[4][4] = {};

    auto stage = [&](int bi, int k0) {
        char* sAp = smem + bi * 32768 + tid * 16;
        char* sBp = sAp + 16384;
#pragma unroll
        for (int i = 0; i < 4; ++i) {   // rows tr + i*32: (tr+i*32)&7 == tr&7
            gload_lds16(gA + (size_t)(i * 32) * lda + k0, sAp + i * 4096);
            gload_lds16(gB + (size_t)(i * 32) * ldb + k0, sBp + i * 4096);
        }
    };
    auto compute = [&](int bi) {
        const char* base = smem + bi * 32768;
        const int swz = (lrow & 7) << 4;
        const int arow = wm * 64 + lrow;
        const int brow = wn * 64 + lrow;
#pragma unroll
        for (int kk = 0; kk < 2; ++kk) {
            const int colb = ((kgrp * 2) | (kk * 64)) ^ swz;
            frag16 af[4], bf[4];
#pragma unroll
            for (int i = 0; i < 4; ++i)
                af[i] = *(const frag16*)(base + (arow + i * 16) * 128 + colb);
#pragma unroll
            for (int j = 0; j < 4; ++j)
                bf[j] = *(const frag16*)(base + 16384 + (brow + j * 16) * 128 + colb);
#pragma unroll
            for (int i = 0; i < 4; ++i)
#pragma unroll
                for (int j = 0; j < 4; ++j)
                    acc[i][j] = __builtin_amdgcn_mfma_f32_16x16x32_f16(af[i], bf[j], acc[i][j], 0, 0, 0);
        }
    };

    stage(0, kbeg);
    int cur = 0;
    const int nt = Ksub >> 6;
#pragma unroll 1
    for (int t = 0; t < nt - 1; ++t) {
        stage(cur ^ 1, kbeg + (t + 1) * 64);
        asm volatile("s_waitcnt vmcnt(8)" ::: "memory");
        __builtin_amdgcn_s_barrier();
        __builtin_amdgcn_sched_barrier(0);
        compute(cur);
        __builtin_amdgcn_s_barrier();
        cur ^= 1;
    }
    asm volatile("s_waitcnt vmcnt(0)" ::: "memory");
    __builtin_amdgcn_s_barrier();
    __builtin_amdgcn_sched_barrier(0);
    compute(cur);
    __builtin_amdgcn_s_barrier();

    const int rbase = (lane >> 4) * 4;
    const size_t cb = (size_t)z * sC;
    if constexpr (TRANS_OUT) {
        float* lt = (float*)smem;   // [64][132]
#pragma unroll
        for (int h = 0; h < 2; ++h) {
            if (wn == h) {
#pragma unroll
                for (int i = 0; i < 4; ++i)
#pragma unroll
                    for (int j = 0; j < 4; ++j)
#pragma unroll
                        for (int r = 0; r < 4; ++r)
                            lt[(j * 16 + lrow) * 132 + wm * 64 + i * 16 + rbase + r] = acc[i][j][r];
            }
            __syncthreads();
#pragma unroll
            for (int it = 0; it < 32; ++it) {
                int idx = it * 256 + tid;
                int nl = idx >> 7, ml = idx & 127;
                int n = n0b + h * 64 + nl;
                float val = lt[nl * 132 + ml] + (BIAS ? bias[n] : 0.f);
                size_t o = cb + (size_t)n * ldc + m0b + ml;
                if constexpr (OUT_F16) ((f16*)C)[o] = (f16)val;
                else                   ((float*)C)[o] = val;
            }
            __syncthreads();
        }
    } else {
#pragma unroll
        for (int j = 0; j < 4; ++j) {
            int col = n0b + wn * 64 + j * 16 + lrow;
            float badd = BIAS ? bias[col] : 0.f;
#pragma unroll
            for (int i = 0; i < 4; ++i) {
                int row = m0b + wm * 64 + i * 16 + rbase;
#pragma unroll
                for (int r = 0; r < 4; ++r) {
                    float val = acc[i][j][r] + badd;
                    size_t o = cb + (size_t)(row + r) * ldc + col;
                    if constexpr (OUT_F16) ((f16*)C)[o] = (f16)val;
                    else                   ((float*)C)[o] = val;
                }
            }
        }
    }
}

// ---------------------------------------------------------------------------
// split-K reduce for PV: cT[b][d][p] = sum_{s<8} Pp[b*8+s][p][d], fp32 -> f16
__global__ __launch_bounds__(256) void reduce_pv(const float* __restrict__ Pp,
                                                 f16* __restrict__ cT) {
    int idx = blockIdx.x * 256 + threadIdx.x;   // 524288 total
    int d = idx & 511, p = (idx >> 9) & 127, b = idx >> 16;
    float s = 0.f;
#pragma unroll
    for (int k = 0; k < 8; ++k)
        s += Pp[(size_t)(b * 8 + k) * 65536 + p * 512 + d];
    cT[(size_t)b * 65536 + d * 128 + p] = (f16)s;
}

// ---------------------------------------------------------------------------
// Fused stage-2: S2 = q.a^T -> in-register softmax -> P2 (f16 LDS) ->
// r = P2.cT^T -> transposed fp32 store to out[b][d][l]. grid dim3(32, 8).
__global__ __launch_bounds__(256) void attn2(
    const f16* __restrict__ qk, const f16* __restrict__ ab,
    const f16* __restrict__ cT, float* __restrict__ out)
{
    __shared__ __align__(16) char smem[69632];
    float* scr = (float*)(smem + 33280);
    f16*   P2  = (f16*)(smem + 34816);

    const int tid = threadIdx.x;
    const int lane = tid & 63, wave = tid >> 6;
    const int wm = wave >> 1, wn = wave & 1;
    const int l0 = blockIdx.x * 128;
    const int b  = blockIdx.y;
    const int lrow = lane & 15, kgrp = (lane >> 4) * 8, rbase = (lane >> 4) * 4;
    const int tr = tid >> 3, tc = (tid & 7) * 8;

    char* sAp = smem + tid * 16;
    char* sBp = smem + 16384 + tid * 16;

    // ---- phase 1: S2 tile = q . a^T ----
    const f16* gA = qk + (size_t)b * 4194304 + (size_t)(l0 + tr) * 1024 + tc;
    const f16* gB = ab + (size_t)b * 65536  + (size_t)tr * 512 + tc;

    f32x4 acc[4][4] = {};
#pragma unroll 1
    for (int k0 = 0; k0 < 512; k0 += 64) {
#pragma unroll
        for (int i = 0; i < 4; ++i) {
            gload_lds16(gA + (size_t)(i * 32) * 1024 + k0, sAp + i * 4096);
            gload_lds16(gB + (size_t)(i * 32) * 512  + k0, sBp + i * 4096);
        }
        __syncthreads();
        const f16* la = (const f16*)smem + (wm * 64 + lrow) * 64 + kgrp;
        const f16* lb = (const f16*)(smem + 16384) + (wn * 64 + lrow) * 64 + kgrp;
#pragma unroll
        for (int kk = 0; kk < 2; ++kk) {
            frag16 af[4], bf[4];
#pragma unroll
            for (int i = 0; i < 4; ++i) af[i] = *(const frag16*)(la + i * 16 * 64 + kk * 32);
#pragma unroll
            for (int j = 0; j < 4; ++j) bf[j] = *(const frag16*)(lb + j * 16 * 64 + kk * 32);
#pragma unroll
            for (int i = 0; i < 4; ++i)
#pragma unroll
                for (int j = 0; j < 4; ++j)
                    acc[i][j] = __builtin_amdgcn_mfma_f32_16x16x32_f16(af[i], bf[j], acc[i][j], 0, 0, 0);
        }
        __syncthreads();
    }

    // ---- phase 2: softmax over N=128 (p), rows are l ----
    float mx[4][4];
#pragma unroll
    for (int i = 0; i < 4; ++i)
#pragma unroll
        for (int r = 0; r < 4; ++r) {
            float m = fmaxf(fmaxf(acc[i][0][r], acc[i][1][r]),
                            fmaxf(acc[i][2][r], acc[i][3][r]));
            m = fmaxf(m, __shfl_xor(m, 1));
            m = fmaxf(m, __shfl_xor(m, 2));
            m = fmaxf(m, __shfl_xor(m, 4));
            m = fmaxf(m, __shfl_xor(m, 8));
            mx[i][r] = m;
        }
    if ((lane & 15) == 0) {
#pragma unroll
        for (int i = 0; i < 4; ++i)
#pragma unroll
            for (int r = 0; r < 4; ++r)
                scr[wn * 128 + wm * 64 + i * 16 + rbase + r] = mx[i][r];
    }
    __syncthreads();
    float rowm[4][4];
#pragma unroll
    for (int i = 0; i < 4; ++i)
#pragma unroll
        for (int r = 0; r < 4; ++r) {
            int row = wm * 64 + i * 16 + rbase + r;
            rowm[i][r] = fmaxf(scr[row], scr[128 + row]);
        }
    __syncthreads();
    float sum[4][4];
#pragma unroll
    for (int i = 0; i < 4; ++i)
#pragma unroll
        for (int r = 0; r < 4; ++r) {
            float s = 0.f;
#pragma unroll
            for (int j = 0; j < 4; ++j) {
                float p = __expf(acc[i][j][r] - rowm[i][r]);
                acc[i][j][r] = p;
                s += p;
            }
            s += __shfl_xor(s, 1);
            s += __shfl_xor(s, 2);
            s += __shfl_xor(s, 4);
            s += __shfl_xor(s, 8);
            sum[i][r] = s;
        }
    if ((lane & 15) == 0) {
#pragma unroll
        for (int i = 0; i < 4; ++i)
#pragma unroll
            for (int r = 0; r < 4; ++r)
                scr[wn * 128 + wm * 64 + i * 16 + rbase + r] = sum[i][r];
    }
    __syncthreads();
#pragma unroll
    for (int i = 0; i < 4; ++i)
#pragma unroll
        for (int r = 0; r < 4; ++r) {
            int row = wm * 64 + i * 16 + rbase + r;
            float inv = 1.f / (scr[row] + scr[128 + row]);
#pragma unroll
            for (int j = 0; j < 4; ++j)
                P2[row * 136 + wn * 64 + j * 16 + lrow] = (f16)(acc[i][j][r] * inv);
        }
    __syncthreads();

    // ---- phase 3: r = P2 . cT^T, 4 chunks of 128 d-cols, K=128 (p) ----
    const f16* gC = cT + (size_t)b * 65536;
    float* outb = out + (size_t)b * 512 * 4096;
#pragma unroll 1
    for (int c = 0; c < 4; ++c) {
        const int d0 = c * 128;
#pragma unroll
        for (int i = 0; i < 4; ++i) {
            gload_lds16(gC + (size_t)(d0 + tr + i * 32) * 128 + tc,      sAp + i * 4096);
            gload_lds16(gC + (size_t)(d0 + tr + i * 32) * 128 + tc + 64, sBp + i * 4096);
        }
        __syncthreads();
        f32x4 a2[4][4] = {};
#pragma unroll
        for (int half = 0; half < 2; ++half) {
            const f16* lb = (const f16*)(smem + half * 16384) + (wn * 64 + lrow) * 64 + kgrp;
            const f16* lpa = P2 + (wm * 64 + lrow) * 136 + half * 64 + kgrp;
#pragma unroll
            for (int kk = 0; kk < 2; ++kk) {
                frag16 af[4], bf[4];
#pragma unroll
                for (int i = 0; i < 4; ++i) af[i] = *(const frag16*)(lpa + i * 16 * 136 + kk * 32);
#pragma unroll
                for (int j = 0; j < 4; ++j) bf[j] = *(const frag16*)(lb + j * 16 * 64 + kk * 32);
#pragma unroll
                for (int i = 0; i < 4; ++i)
#pragma unroll
                    for (int j = 0; j < 4; ++j)
                        a2[i][j] = __builtin_amdgcn_mfma_f32_16x16x32_f16(af[i], bf[j], a2[i][j], 0, 0, 0);
            }
        }
        __syncthreads();

        float* lt = (float*)smem;   // [64][132]
#pragma unroll
        for (int h = 0; h < 2; ++h) {
            if (wn == h) {
#pragma unroll
                for (int i = 0; i < 4; ++i)
#pragma unroll
                    for (int j = 0; j < 4; ++j)
#pragma unroll
                        for (int r = 0; r < 4; ++r)
                            lt[(j * 16 + lrow) * 132 + wm * 64 + i * 16 + rbase + r] = a2[i][j][r];
            }
            __syncthreads();
#pragma unroll
            for (int it = 0; it < 32; ++it) {
                int idx = it * 256 + tid;
                int nl = idx >> 7, ml = idx & 127;
                outb[(size_t)(d0 + h * 64 + nl) * 4096 + l0 + ml] = lt[nl * 132 + ml];
            }
            __syncthreads();
        }
    }
}

// ---------------------------------------------------------------------------
extern "C" void kernel_launch(void* const* d_in, const int* in_sizes, int n_in,
                              void* d_out, int out_size, void* d_ws, size_t ws_size,
                              hipStream_t stream) {
    // B=8, D=512, L=4096, P=128, BL=32768
    const float* x  = (const float*)d_in[0];
    const float* Wq = (const float*)d_in[1];
    const float* bq = (const float*)d_in[2];
    const float* Wk = (const float*)d_in[3];
    const float* bk = (const float*)d_in[4];
    const float* Wv = (const float*)d_in[5];
    const float* bv = (const float*)d_in[6];
    float* out = (float*)d_out;

    const size_t o_xb = 0;                    // 32MB f16 [32768][512]
    const size_t o_qk = 33554432;             // 64MB f16 [32768][1024] (q cols 0-511, k cols 512-1023)
    const size_t o_vT = 100663296;            // 32MB f16 [8][512][4096]
    const size_t o_w  = 134217728;            // wqkv f16 [1536][512], 1.5MB
    const size_t o_ab = o_w + 1572864;        // a f16 [8][128][512], 1MB
    const size_t o_cT = o_ab + 1048576;       // cT f16 [8][512][128], 1MB
    const size_t o_S  = o_cT + 1048576;       // scores fp32 16MB (S1, then PV partials)
    const size_t o_P  = o_S + 16777216;       // probs f16, 8MB (P1)
    const size_t need = o_P + 8388608;        // ~155.5 MB
    if (ws_size < need) return;

    char* ws = (char*)d_ws;
    f16* xb   = (f16*)(ws + o_xb);
    f16* qk   = (f16*)(ws + o_qk);
    f16* vT   = (f16*)(ws + o_vT);
    f16* wqkv = (f16*)(ws + o_w);
    f16* ab   = (f16*)(ws + o_ab);
    f16* cT   = (f16*)(ws + o_cT);
    float* Sb = (float*)(ws + o_S);
    float* Pp = (float*)(ws + o_S);           // PV partials alias S (disjoint lifetime)
    f16* Pb   = (f16*)(ws + o_P);

    // 1. weights fp32 -> f16 packed [Wq;Wk;Wv], one launch
    cvt3_f16<<<3072, 256, 0, stream>>>(Wq, Wk, Wv, wqkv);

    // 2. x [B][D][L] -> xb [B][L][D] f16
    transpose_f32_f16<<<dim3(8, 64, 8), 256, 0, stream>>>(x, xb);

    // 3. fused QKV projection (M=32768, N=1536, K=512) + fused avg-pool -> ab
    //    XCD-grouped grid: x = XCD slot (8), y = n-tile (12), z = m-chunk (32)
    gemm_qkv<<<dim3(8, 12, 32), 512, 0, stream>>>(xb, wqkv, bq, bk, bv, qk, vT, ab);

    // 4. stage-1 scores: S1[b][p][l] = a . k  (M=128,N=4096,K=512)
    gemm_lds<false, false, false><<<dim3(1, 32, 8), 256, 0, stream>>>(
        ab, qk + 512, nullptr, Sb, 512, 512, 1024, 4096, 65536LL, 4194304LL, 524288LL, 1);

    // 5. softmax over l -> P1 f16
    softmax4096<<<1024, 256, 0, stream>>>(Sb, Pb);

    // 6. PV split-K partials: Pp[b*8+s][p][d] (M=128,N=512,K=4096,splitk=8)
    gemm_lds<false, false, false><<<dim3(1, 4, 64), 256, 0, stream>>>(
        Pb, vT, nullptr, Pp, 4096, 4096, 4096, 512, 524288LL, 2097152LL, 65536LL, 8);
    // 6r. reduce + transpose -> cT[b][d][p] f16
    reduce_pv<<<2048, 256, 0, stream>>>(Pp, cT);

    // 7. fused stage-2: S2 -> softmax -> P2.cT^T -> out[b][d][l]
    attn2<<<dim3(32, 8), 256, 0, stream>>>(qk, ab, cT, out);
}

// Round 17
// 159.873 us; speedup vs baseline: 1.2618x; 1.0282x over previous
//
#include <hip/hip_runtime.h>
#include <hip/hip_fp16.h>

typedef _Float16 f16;
using frag16 = __attribute__((ext_vector_type(8))) _Float16;  // 8 f16 (4 VGPRs)
using f32x4  = __attribute__((ext_vector_type(4))) float;     // MFMA accumulator

// async global->LDS, 16B per lane.
__device__ __forceinline__ void gload_lds16(const void* g, void* l) {
    __builtin_amdgcn_global_load_lds(
        (const __attribute__((address_space(1))) void*)g,
        (__attribute__((address_space(3))) void*)l, 16, 0, 0);
}

// ---------------------------------------------------------------------------
// fp32 -> f16 convert for all three weight matrices in one launch.
__global__ __launch_bounds__(256) void cvt3_f16(const float* __restrict__ Wq,
                                                const float* __restrict__ Wk,
                                                const float* __restrict__ Wv,
                                                f16* __restrict__ out) {
    int i = blockIdx.x * 256 + threadIdx.x;     // 0..786431
    const float* src = (i < 262144) ? Wq : (i < 524288) ? Wk : Wv;
    out[i] = (f16)src[i & 262143];
}

// ---------------------------------------------------------------------------
// x [B][512][4096] fp32 -> xb [B][4096][512] f16  (64x64 LDS tile)
// float4 loads, uint4 (8xf16) stores.
__global__ __launch_bounds__(256) void transpose_f32_f16(const float* __restrict__ in,
                                                         f16* __restrict__ out) {
    __shared__ float t[64][65];
    const int b = blockIdx.z;
    const int d0 = blockIdx.x * 64, l0 = blockIdx.y * 64;
    const float* ip = in + (size_t)b * 512 * 4096;
    f16* op = out + (size_t)b * 4096 * 512;
#pragma unroll
    for (int it = 0; it < 4; ++it) {
        int idx = it * 256 + threadIdx.x;
        int d = idx >> 4, c4 = (idx & 15) * 4;
        const float4 v = *reinterpret_cast<const float4*>(&ip[(size_t)(d0 + d) * 4096 + l0 + c4]);
        t[d][c4] = v.x; t[d][c4 + 1] = v.y; t[d][c4 + 2] = v.z; t[d][c4 + 3] = v.w;
    }
    __syncthreads();
#pragma unroll
    for (int it = 0; it < 2; ++it) {
        int idx = it * 256 + threadIdx.x;
        int l = idx >> 3, dg = (idx & 7) * 8;
        union { f16 h[8]; uint4 u; } pk;
#pragma unroll
        for (int k = 0; k < 8; ++k) pk.h[k] = (f16)t[dg + k][l];
        *reinterpret_cast<uint4*>(&op[(size_t)(l0 + l) * 512 + d0 + dg]) = pk.u;
    }
}

// ---------------------------------------------------------------------------
// row softmax, len=4096: fp32 in -> f16 probs. one block (256 thr) per row
__global__ __launch_bounds__(256) void softmax4096(const float* __restrict__ S,
                                                   f16* __restrict__ P) {
    const float* s = S + (size_t)blockIdx.x * 4096;
    f16* p = P + (size_t)blockIdx.x * 4096;
    const int tid = threadIdx.x;
    float v[16];
    float mx = -3.0e38f;
#pragma unroll
    for (int i = 0; i < 16; ++i) { v[i] = s[i * 256 + tid]; mx = fmaxf(mx, v[i]); }
#pragma unroll
    for (int o = 32; o; o >>= 1) mx = fmaxf(mx, __shfl_xor(mx, o));
    __shared__ float redm[4];
    __shared__ float reds[4];
    if ((tid & 63) == 0) redm[tid >> 6] = mx;
    __syncthreads();
    mx = fmaxf(fmaxf(redm[0], redm[1]), fmaxf(redm[2], redm[3]));
    float sum = 0.f;
#pragma unroll
    for (int i = 0; i < 16; ++i) { v[i] = __expf(v[i] - mx); sum += v[i]; }
#pragma unroll
    for (int o = 32; o; o >>= 1) sum += __shfl_xor(sum, o);
    if ((tid & 63) == 0) reds[tid >> 6] = sum;
    __syncthreads();
    sum = reds[0] + reds[1] + reds[2] + reds[3];
    float inv = 1.f / sum;
#pragma unroll
    for (int i = 0; i < 16; ++i) p[i * 256 + tid] = (f16)(v[i] * inv);
}

// ---------------------------------------------------------------------------
// Fused QKV projection — 8-wave / 512-thread, double-buffered prefetch K-loop
// + T2 LDS XOR-swizzle (linear gload_lds dest, pre-swizzled global SOURCE
// chunk (t&7)^(tr&7), swizzled READ col ^((lrow&7)<<4)).
// vT epilogue stores packed as uint4 (8 f16).
// XCD grouping in grid shape: grid dim3(8, 12, 32).
__global__ __launch_bounds__(512) void gemm_qkv(
    const f16* __restrict__ xb, const f16* __restrict__ w,
    const float* __restrict__ bq, const float* __restrict__ bk,
    const float* __restrict__ bv,
    f16* __restrict__ qk, f16* __restrict__ vT, f16* __restrict__ a)
{
    __shared__ __align__(16) char smem[65536];   // 2 x (16KB A + 16KB B); epilogue aliases
    const int tid = threadIdx.x;                 // 0..511
    const int lane = tid & 63, wave = tid >> 6;  // 8 waves
    const int wm = wave >> 2, wn = wave & 3;     // 2m x 4n

    const int m0b = ((blockIdx.z << 3) + blockIdx.x) << 7;   // m_tile*128
    const int n0b = blockIdx.y << 7;                          // n_tile*128

    const int lrow = lane & 15, kgrp = (lane >> 4) * 8;

    // staging: thread t covers rows tr, tr+64; SOURCE chunk pre-swizzled
    const int tr = tid >> 3;
    const int tcs = (((tid & 7) ^ (tr & 7)) * 8);   // swizzled f16 col
    const f16* gA = xb + (size_t)(m0b + tr) * 512 + tcs;
    const f16* gB = w  + (size_t)(n0b + tr) * 512 + tcs;

    f32x4 acc[4][2] = {};

    auto stage = [&](int bi, int k0) {
        char* sAp = smem + bi * 32768 + tid * 16;
        char* sBp = sAp + 16384;
        gload_lds16(gA + k0,                     sAp);
        gload_lds16(gA + (size_t)64 * 512 + k0,  sAp + 8192);   // (tr+64)&7 == tr&7
        gload_lds16(gB + k0,                     sBp);
        gload_lds16(gB + (size_t)64 * 512 + k0,  sBp + 8192);
    };
    auto compute = [&](int bi) {
        const char* base = smem + bi * 32768;
        const int swz = (lrow & 7) << 4;
        const int arow = wm * 64 + lrow;
        const int brow = wn * 32 + lrow;
#pragma unroll
        for (int kk = 0; kk < 2; ++kk) {
            const int colb = ((kgrp * 2) | (kk * 64)) ^ swz;   // swizzled byte col
            frag16 af[4], bf[2];
#pragma unroll
            for (int i = 0; i < 4; ++i)
                af[i] = *(const frag16*)(base + (arow + i * 16) * 128 + colb);
#pragma unroll
            for (int j = 0; j < 2; ++j)
                bf[j] = *(const frag16*)(base + 16384 + (brow + j * 16) * 128 + colb);
#pragma unroll
            for (int i = 0; i < 4; ++i)
#pragma unroll
                for (int j = 0; j < 2; ++j)
                    acc[i][j] = __builtin_amdgcn_mfma_f32_16x16x32_f16(af[i], bf[j], acc[i][j], 0, 0, 0);
        }
    };

    stage(0, 0);
    int cur = 0;
#pragma unroll 1
    for (int t = 0; t < 7; ++t) {
        stage(cur ^ 1, (t + 1) * 64);                      // prefetch next tile
        asm volatile("s_waitcnt vmcnt(4)" ::: "memory");   // wait current tile only
        __builtin_amdgcn_s_barrier();
        __builtin_amdgcn_sched_barrier(0);
        compute(cur);
        __builtin_amdgcn_s_barrier();                      // readers done before overwrite
        cur ^= 1;
    }
    asm volatile("s_waitcnt vmcnt(0)" ::: "memory");
    __builtin_amdgcn_s_barrier();
    __builtin_amdgcn_sched_barrier(0);
    compute(cur);
    __builtin_amdgcn_s_barrier();                          // before epilogue reuses smem

    const int rbase = (lane >> 4) * 4;
    if (n0b < 1024) {
        const float* bptr = (n0b < 512) ? bq : bk;

        // fused AdaptiveAvgPool (q-part only)
        if (n0b < 512) {
            const int b = m0b >> 12;
            const int pbase = ((m0b & 4095) >> 5) + wm * 2;
#pragma unroll
            for (int j = 0; j < 2; ++j) {
                int d = n0b + wn * 32 + j * 16 + lrow;
                float badd = bptr[d];
                float s0 = 0.f, s1 = 0.f;
#pragma unroll
                for (int r = 0; r < 4; ++r) {
                    s0 += acc[0][j][r] + acc[1][j][r];
                    s1 += acc[2][j][r] + acc[3][j][r];
                }
                s0 += __shfl_xor(s0, 16); s0 += __shfl_xor(s0, 32);
                s1 += __shfl_xor(s1, 16); s1 += __shfl_xor(s1, 32);
                if (lane < 16) {
                    a[((size_t)(b * 128 + pbase)     * 512) + d] = (f16)(s0 * 0.03125f + badd);
                    a[((size_t)(b * 128 + pbase + 1) * 512) + d] = (f16)(s1 * 0.03125f + badd);
                }
            }
        }

        // coalesced qk store via LDS staging: f16 tile [128][136]
        f16* lt = (f16*)smem;
#pragma unroll
        for (int j = 0; j < 2; ++j) {
            int col = wn * 32 + j * 16 + lrow;
            float badd = bptr[(n0b + col) & 511];
#pragma unroll
            for (int i = 0; i < 4; ++i) {
                int row = wm * 64 + i * 16 + rbase;
#pragma unroll
                for (int r = 0; r < 4; ++r)
                    lt[(row + r) * 136 + col] = (f16)(acc[i][j][r] + badd);
            }
        }
        __syncthreads();
#pragma unroll
        for (int it = 0; it < 4; ++it) {
            int cu = it * 512 + tid;            // 2048 chunks of 8 f16
            int row = cu >> 4, c8 = (cu & 15) * 8;
            *reinterpret_cast<uint4*>(&qk[(size_t)(m0b + row) * 1024 + n0b + c8]) =
                *reinterpret_cast<const uint4*>(&lt[row * 136 + c8]);
        }
    } else {
        const int b = m0b >> 12, l0 = m0b & 4095;
        const int d0 = n0b - 1024;
        f16* vout = vT + (size_t)b * 2097152 + l0;
        float* lt = (float*)smem;   // [64][132] fp32
#pragma unroll
        for (int h = 0; h < 2; ++h) {
            if ((wn >> 1) == h) {
#pragma unroll
                for (int i = 0; i < 4; ++i)
#pragma unroll
                    for (int j = 0; j < 2; ++j)
#pragma unroll
                        for (int r = 0; r < 4; ++r)
                            lt[((wn & 1) * 32 + j * 16 + lrow) * 132 + wm * 64 + i * 16 + rbase + r]
                                = acc[i][j][r];
            }
            __syncthreads();
            // packed stores: 1024 uint4 (8 f16) per half, 512 threads x 2
#pragma unroll
            for (int it = 0; it < 2; ++it) {
                int idx = it * 512 + tid;       // 1024 = 64 rows x 16 groups
                int nl = idx >> 4, mg = (idx & 15) * 8;
                int d = d0 + h * 64 + nl;
                float badd = bv[d];
                union { f16 hh[8]; uint4 u; } pk;
#pragma unroll
                for (int k = 0; k < 8; ++k)
                    pk.hh[k] = (f16)(lt[nl * 132 + mg + k] + badd);
                *reinterpret_cast<uint4*>(&vout[(size_t)d * 4096 + mg]) = pk.u;
            }
            __syncthreads();
        }
    }
}

// ---------------------------------------------------------------------------
// Generic NT GEMM — prefetched double-buffer K-loop + T2 swizzle (same scheme).
// gA/gB do NOT include kbeg — stage() receives the absolute k offset.
template<bool OUT_F16, bool BIAS, bool TRANS_OUT>
__global__ __launch_bounds__(256) void gemm_lds(
    const f16* __restrict__ A, const f16* __restrict__ B,
    const float* __restrict__ bias, void* __restrict__ C,
    int K, int lda, int ldb, int ldc,
    long long sA, long long sB, long long sC, int splitk)
{
    __shared__ __align__(16) char smem[65536];
    const int z = blockIdx.z;
    const int batch = z / splitk;
    const int ks = z - batch * splitk;
    const int Ksub = K / splitk;
    const int kbeg = ks * Ksub;

    const f16* Ab = A + (size_t)batch * sA;
    const f16* Bb = B + (size_t)batch * sB;

    const int tid = threadIdx.x;
    const int lane = tid & 63, wave = tid >> 6;
    const int wm = wave >> 1, wn = wave & 1;
    const int m0b = blockIdx.x * 128, n0b = blockIdx.y * 128;
    const int lrow = lane & 15, kgrp = (lane >> 4) * 8;

    const int tr = tid >> 3;
    const int tcs = (((tid & 7) ^ (tr & 7)) * 8);   // swizzled source col
    const f16* gA = Ab + (size_t)(m0b + tr) * lda + tcs;
    const f16* gB = Bb + (size_t)(n0b + tr) * ldb + tcs;

    f32x4 acc[4][4] = {};

    auto stage = [&](int bi, int k0) {
        char* sAp = smem + bi * 32768 + tid * 16;
        char* sBp = sAp + 16384;
#pragma unroll
        for (int i = 0; i < 4; ++i) {   // rows tr + i*32: (tr+i*32)&7 == tr&7
            gload_lds16(gA + (size_t)(i * 32) * lda + k0, sAp + i * 4096);
            gload_lds16(gB + (size_t)(i * 32) * ldb + k0, sBp + i * 4096);
        }
    };
    auto compute = [&](int bi) {
        const char* base = smem + bi * 32768;
        const int swz = (lrow & 7) << 4;
        const int arow = wm * 64 + lrow;
        const int brow = wn * 64 + lrow;
#pragma unroll
        for (int kk = 0; kk < 2; ++kk) {
            const int colb = ((kgrp * 2) | (kk * 64)) ^ swz;
            frag16 af[4], bf[4];
#pragma unroll
            for (int i = 0; i < 4; ++i)
                af[i] = *(const frag16*)(base + (arow + i * 16) * 128 + colb);
#pragma unroll
            for (int j = 0; j < 4; ++j)
                bf[j] = *(const frag16*)(base + 16384 + (brow + j * 16) * 128 + colb);
#pragma unroll
            for (int i = 0; i < 4; ++i)
#pragma unroll
                for (int j = 0; j < 4; ++j)
                    acc[i][j] = __builtin_amdgcn_mfma_f32_16x16x32_f16(af[i], bf[j], acc[i][j], 0, 0, 0);
        }
    };

    stage(0, kbeg);
    int cur = 0;
    const int nt = Ksub >> 6;
#pragma unroll 1
    for (int t = 0; t < nt - 1; ++t) {
        stage(cur ^ 1, kbeg + (t + 1) * 64);
        asm volatile("s_waitcnt vmcnt(8)" ::: "memory");
        __builtin_amdgcn_s_barrier();
        __builtin_amdgcn_sched_barrier(0);
        compute(cur);
        __builtin_amdgcn_s_barrier();
        cur ^= 1;
    }
    asm volatile("s_waitcnt vmcnt(0)" ::: "memory");
    __builtin_amdgcn_s_barrier();
    __builtin_amdgcn_sched_barrier(0);
    compute(cur);
    __builtin_amdgcn_s_barrier();

    const int rbase = (lane >> 4) * 4;
    const size_t cb = (size_t)z * sC;
    if constexpr (TRANS_OUT) {
        float* lt = (float*)smem;   // [64][132]
#pragma unroll
        for (int h = 0; h < 2; ++h) {
            if (wn == h) {
#pragma unroll
                for (int i = 0; i < 4; ++i)
#pragma unroll
                    for (int j = 0; j < 4; ++j)
#pragma unroll
                        for (int r = 0; r < 4; ++r)
                            lt[(j * 16 + lrow) * 132 + wm * 64 + i * 16 + rbase + r] = acc[i][j][r];
            }
            __syncthreads();
#pragma unroll
            for (int it = 0; it < 32; ++it) {
                int idx = it * 256 + tid;
                int nl = idx >> 7, ml = idx & 127;
                int n = n0b + h * 64 + nl;
                float val = lt[nl * 132 + ml] + (BIAS ? bias[n] : 0.f);
                size_t o = cb + (size_t)n * ldc + m0b + ml;
                if constexpr (OUT_F16) ((f16*)C)[o] = (f16)val;
                else                   ((float*)C)[o] = val;
            }
            __syncthreads();
        }
    } else {
#pragma unroll
        for (int j = 0; j < 4; ++j) {
            int col = n0b + wn * 64 + j * 16 + lrow;
            float badd = BIAS ? bias[col] : 0.f;
#pragma unroll
            for (int i = 0; i < 4; ++i) {
                int row = m0b + wm * 64 + i * 16 + rbase;
#pragma unroll
                for (int r = 0; r < 4; ++r) {
                    float val = acc[i][j][r] + badd;
                    size_t o = cb + (size_t)(row + r) * ldc + col;
                    if constexpr (OUT_F16) ((f16*)C)[o] = (f16)val;
                    else                   ((float*)C)[o] = val;
                }
            }
        }
    }
}

// ---------------------------------------------------------------------------
// split-K reduce for PV: cT[b][d][p] = sum_{s<8} Pp[b*8+s][p][d], fp32 -> f16
__global__ __launch_bounds__(256) void reduce_pv(const float* __restrict__ Pp,
                                                 f16* __restrict__ cT) {
    int idx = blockIdx.x * 256 + threadIdx.x;   // 524288 total
    int d = idx & 511, p = (idx >> 9) & 127, b = idx >> 16;
    float s = 0.f;
#pragma unroll
    for (int k = 0; k < 8; ++k)
        s += Pp[(size_t)(b * 8 + k) * 65536 + p * 512 + d];
    cT[(size_t)b * 65536 + d * 128 + p] = (f16)s;
}

// ---------------------------------------------------------------------------
// Fused stage-2: S2 = q.a^T -> in-register softmax -> P2 (f16 LDS) ->
// r = P2.cT^T -> transposed fp32 store to out[b][d][l]. grid dim3(32, 8).
// Out stores packed as float4.
__global__ __launch_bounds__(256) void attn2(
    const f16* __restrict__ qk, const f16* __restrict__ ab,
    const f16* __restrict__ cT, float* __restrict__ out)
{
    __shared__ __align__(16) char smem[69632];
    float* scr = (float*)(smem + 33280);
    f16*   P2  = (f16*)(smem + 34816);

    const int tid = threadIdx.x;
    const int lane = tid & 63, wave = tid >> 6;
    const int wm = wave >> 1, wn = wave & 1;
    const int l0 = blockIdx.x * 128;
    const int b  = blockIdx.y;
    const int lrow = lane & 15, kgrp = (lane >> 4) * 8, rbase = (lane >> 4) * 4;
    const int tr = tid >> 3, tc = (tid & 7) * 8;

    char* sAp = smem + tid * 16;
    char* sBp = smem + 16384 + tid * 16;

    // ---- phase 1: S2 tile = q . a^T ----
    const f16* gA = qk + (size_t)b * 4194304 + (size_t)(l0 + tr) * 1024 + tc;
    const f16* gB = ab + (size_t)b * 65536  + (size_t)tr * 512 + tc;

    f32x4 acc[4][4] = {};
#pragma unroll 1
    for (int k0 = 0; k0 < 512; k0 += 64) {
#pragma unroll
        for (int i = 0; i < 4; ++i) {
            gload_lds16(gA + (size_t)(i * 32) * 1024 + k0, sAp + i * 4096);
            gload_lds16(gB + (size_t)(i * 32) * 512  + k0, sBp + i * 4096);
        }
        __syncthreads();
        const f16* la = (const f16*)smem + (wm * 64 + lrow) * 64 + kgrp;
        const f16* lb = (const f16*)(smem + 16384) + (wn * 64 + lrow) * 64 + kgrp;
#pragma unroll
        for (int kk = 0; kk < 2; ++kk) {
            frag16 af[4], bf[4];
#pragma unroll
            for (int i = 0; i < 4; ++i) af[i] = *(const frag16*)(la + i * 16 * 64 + kk * 32);
#pragma unroll
            for (int j = 0; j < 4; ++j) bf[j] = *(const frag16*)(lb + j * 16 * 64 + kk * 32);
#pragma unroll
            for (int i = 0; i < 4; ++i)
#pragma unroll
                for (int j = 0; j < 4; ++j)
                    acc[i][j] = __builtin_amdgcn_mfma_f32_16x16x32_f16(af[i], bf[j], acc[i][j], 0, 0, 0);
        }
        __syncthreads();
    }

    // ---- phase 2: softmax over N=128 (p), rows are l ----
    float mx[4][4];
#pragma unroll
    for (int i = 0; i < 4; ++i)
#pragma unroll
        for (int r = 0; r < 4; ++r) {
            float m = fmaxf(fmaxf(acc[i][0][r], acc[i][1][r]),
                            fmaxf(acc[i][2][r], acc[i][3][r]));
            m = fmaxf(m, __shfl_xor(m, 1));
            m = fmaxf(m, __shfl_xor(m, 2));
            m = fmaxf(m, __shfl_xor(m, 4));
            m = fmaxf(m, __shfl_xor(m, 8));
            mx[i][r] = m;
        }
    if ((lane & 15) == 0) {
#pragma unroll
        for (int i = 0; i < 4; ++i)
#pragma unroll
            for (int r = 0; r < 4; ++r)
                scr[wn * 128 + wm * 64 + i * 16 + rbase + r] = mx[i][r];
    }
    __syncthreads();
    float rowm[4][4];
#pragma unroll
    for (int i = 0; i < 4; ++i)
#pragma unroll
        for (int r = 0; r < 4; ++r) {
            int row = wm * 64 + i * 16 + rbase + r;
            rowm[i][r] = fmaxf(scr[row], scr[128 + row]);
        }
    __syncthreads();
    float sum[4][4];
#pragma unroll
    for (int i = 0; i < 4; ++i)
#pragma unroll
        for (int r = 0; r < 4; ++r) {
            float s = 0.f;
#pragma unroll
            for (int j = 0; j < 4; ++j) {
                float p = __expf(acc[i][j][r] - rowm[i][r]);
                acc[i][j][r] = p;
                s += p;
            }
            s += __shfl_xor(s, 1);
            s += __shfl_xor(s, 2);
            s += __shfl_xor(s, 4);
            s += __shfl_xor(s, 8);
            sum[i][r] = s;
        }
    if ((lane & 15) == 0) {
#pragma unroll
        for (int i = 0; i < 4; ++i)
#pragma unroll
            for (int r = 0; r < 4; ++r)
                scr[wn * 128 + wm * 64 + i * 16 + rbase + r] = sum[i][r];
    }
    __syncthreads();
#pragma unroll
    for (int i = 0; i < 4; ++i)
#pragma unroll
        for (int r = 0; r < 4; ++r) {
            int row = wm * 64 + i * 16 + rbase + r;
            float inv = 1.f / (scr[row] + scr[128 + row]);
#pragma unroll
            for (int j = 0; j < 4; ++j)
                P2[row * 136 + wn * 64 + j * 16 + lrow] = (f16)(acc[i][j][r] * inv);
        }
    __syncthreads();

    // ---- phase 3: r = P2 . cT^T, 4 chunks of 128 d-cols, K=128 (p) ----
    const f16* gC = cT + (size_t)b * 65536;
    float* outb = out + (size_t)b * 512 * 4096;
#pragma unroll 1
    for (int c = 0; c < 4; ++c) {
        const int d0 = c * 128;
#pragma unroll
        for (int i = 0; i < 4; ++i) {
            gload_lds16(gC + (size_t)(d0 + tr + i * 32) * 128 + tc,      sAp + i * 4096);
            gload_lds16(gC + (size_t)(d0 + tr + i * 32) * 128 + tc + 64, sBp + i * 4096);
        }
        __syncthreads();
        f32x4 a2[4][4] = {};
#pragma unroll
        for (int half = 0; half < 2; ++half) {
            const f16* lb = (const f16*)(smem + half * 16384) + (wn * 64 + lrow) * 64 + kgrp;
            const f16* lpa = P2 + (wm * 64 + lrow) * 136 + half * 64 + kgrp;
#pragma unroll
            for (int kk = 0; kk < 2; ++kk) {
                frag16 af[4], bf[4];
#pragma unroll
                for (int i = 0; i < 4; ++i) af[i] = *(const frag16*)(lpa + i * 16 * 136 + kk * 32);
#pragma unroll
                for (int j = 0; j < 4; ++j) bf[j] = *(const frag16*)(lb + j * 16 * 64 + kk * 32);
#pragma unroll
                for (int i = 0; i < 4; ++i)
#pragma unroll
                    for (int j = 0; j < 4; ++j)
                        a2[i][j] = __builtin_amdgcn_mfma_f32_16x16x32_f16(af[i], bf[j], a2[i][j], 0, 0, 0);
            }
        }
        __syncthreads();

        float* lt = (float*)smem;   // [64][132]
#pragma unroll
        for (int h = 0; h < 2; ++h) {
            if (wn == h) {
#pragma unroll
                for (int i = 0; i < 4; ++i)
#pragma unroll
                    for (int j = 0; j < 4; ++j)
#pragma unroll
                        for (int r = 0; r < 4; ++r)
                            lt[(j * 16 + lrow) * 132 + wm * 64 + i * 16 + rbase + r] = a2[i][j][r];
            }
            __syncthreads();
            // packed float4 stores: 2048 per half, 256 threads x 8
#pragma unroll
            for (int it = 0; it < 8; ++it) {
                int idx = it * 256 + tid;
                int nl = idx >> 5, mq = (idx & 31) * 4;
                float4 v = *reinterpret_cast<const float4*>(&lt[nl * 132 + mq]);
                *reinterpret_cast<float4*>(&outb[(size_t)(d0 + h * 64 + nl) * 4096 + l0 + mq]) = v;
            }
            __syncthreads();
        }
    }
}

// ---------------------------------------------------------------------------
extern "C" void kernel_launch(void* const* d_in, const int* in_sizes, int n_in,
                              void* d_out, int out_size, void* d_ws, size_t ws_size,
                              hipStream_t stream) {
    // B=8, D=512, L=4096, P=128, BL=32768
    const float* x  = (const float*)d_in[0];
    const float* Wq = (const float*)d_in[1];
    const float* bq = (const float*)d_in[2];
    const float* Wk = (const float*)d_in[3];
    const float* bk = (const float*)d_in[4];
    const float* Wv = (const float*)d_in[5];
    const float* bv = (const float*)d_in[6];
    float* out = (float*)d_out;

    const size_t o_xb = 0;                    // 32MB f16 [32768][512]
    const size_t o_qk = 33554432;             // 64MB f16 [32768][1024] (q cols 0-511, k cols 512-1023)
    const size_t o_vT = 100663296;            // 32MB f16 [8][512][4096]
    const size_t o_w  = 134217728;            // wqkv f16 [1536][512], 1.5MB
    const size_t o_ab = o_w + 1572864;        // a f16 [8][128][512], 1MB
    const size_t o_cT = o_ab + 1048576;       // cT f16 [8][512][128], 1MB
    const size_t o_S  = o_cT + 1048576;       // scores fp32 16MB (S1, then PV partials)
    const size_t o_P  = o_S + 16777216;       // probs f16, 8MB (P1)
    const size_t need = o_P + 8388608;        // ~155.5 MB
    if (ws_size < need) return;

    char* ws = (char*)d_ws;
    f16* xb   = (f16*)(ws + o_xb);
    f16* qk   = (f16*)(ws + o_qk);
    f16* vT   = (f16*)(ws + o_vT);
    f16* wqkv = (f16*)(ws + o_w);
    f16* ab   = (f16*)(ws + o_ab);
    f16* cT   = (f16*)(ws + o_cT);
    float* Sb = (float*)(ws + o_S);
    float* Pp = (float*)(ws + o_S);           // PV partials alias S (disjoint lifetime)
    f16* Pb   = (f16*)(ws + o_P);

    // 1. weights fp32 -> f16 packed [Wq;Wk;Wv], one launch
    cvt3_f16<<<3072, 256, 0, stream>>>(Wq, Wk, Wv, wqkv);

    // 2. x [B][D][L] -> xb [B][L][D] f16
    transpose_f32_f16<<<dim3(8, 64, 8), 256, 0, stream>>>(x, xb);

    // 3. fused QKV projection (M=32768, N=1536, K=512) + fused avg-pool -> ab
    //    XCD-grouped grid: x = XCD slot (8), y = n-tile (12), z = m-chunk (32)
    gemm_qkv<<<dim3(8, 12, 32), 512, 0, stream>>>(xb, wqkv, bq, bk, bv, qk, vT, ab);

    // 4. stage-1 scores: S1[b][p][l] = a . k  (M=128,N=4096,K=512)
    gemm_lds<false, false, false><<<dim3(1, 32, 8), 256, 0, stream>>>(
        ab, qk + 512, nullptr, Sb, 512, 512, 1024, 4096, 65536LL, 4194304LL, 524288LL, 1);

    // 5. softmax over l -> P1 f16
    softmax4096<<<1024, 256, 0, stream>>>(Sb, Pb);

    // 6. PV split-K partials: Pp[b*8+s][p][d] (M=128,N=512,K=4096,splitk=8)
    gemm_lds<false, false, false><<<dim3(1, 4, 64), 256, 0, stream>>>(
        Pb, vT, nullptr, Pp, 4096, 4096, 4096, 512, 524288LL, 2097152LL, 65536LL, 8);
    // 6r. reduce + transpose -> cT[b][d][p] f16
    reduce_pv<<<2048, 256, 0, stream>>>(Pp, cT);

    // 7. fused stage-2: S2 -> softmax -> P2.cT^T -> out[b][d][l]
    attn2<<<dim3(32, 8), 256, 0, stream>>>(qk, ab, cT, out);
}